// Round 1
// baseline (627.309 us; speedup 1.0000x reference)
//
#include <hip/hip_runtime.h>

// ---------------------------------------------------------------------------
// Mutual Feature Refinement (two cross-attention CAN modules)
// B=16, C=512, CI=256, num=H*W=1024
// Round 0: correctness-first bf16 MFMA pipeline, materialized intermediates.
// ---------------------------------------------------------------------------

typedef __bf16 bf16x8 __attribute__((ext_vector_type(8)));
typedef float  f32x4  __attribute__((ext_vector_type(4)));
static_assert(sizeof(bf16x8) == 16, "bf16x8 must be 16B");

__device__ __forceinline__ ushort f2bf(float x) {
  unsigned u = __builtin_bit_cast(unsigned, x);
  u = (u + 0x7fffu + ((u >> 16) & 1u)) >> 16;   // RNE
  return (ushort)u;
}

// ---------------------------------------------------------------------------
// Generic MFMA GEMM:  D[m'][n'] = sum_k A[m'][k] * Bt[n'][k]   (both row-major,
// K-contiguous), stored TRANSPOSED:  C[n'*ldc + m']  (per-lane contiguous x4).
// BIASM: 0 = none, 1 = bias per n' (col of store), 2 = bias per m' (row of store)
// ---------------------------------------------------------------------------
template <bool F32OUT, int BIASM>
__global__ __launch_bounds__(256) void gemm_tt(
    const ushort* __restrict__ A, size_t sA,
    const ushort* __restrict__ Bt, size_t sB,
    void* __restrict__ Cv, size_t sC,
    const float* __restrict__ bias,
    int K, int ldc)
{
  const int b = blockIdx.z;
  const ushort* Ab = A + (size_t)b * sA;
  const ushort* Bb = Bt + (size_t)b * sB;
  const int lane = threadIdx.x & 63;
  const int wid  = threadIdx.x >> 6;
  const int m0 = blockIdx.x * 64 + (wid >> 1) * 32;
  const int n0 = blockIdx.y * 64 + (wid & 1) * 32;
  const int lr = lane & 15;
  const int ko = (lane >> 4) * 8;

  const ushort* pa0 = Ab + (size_t)(m0 + lr) * K + ko;
  const ushort* pa1 = pa0 + (size_t)16 * K;
  const ushort* pb0 = Bb + (size_t)(n0 + lr) * K + ko;
  const ushort* pb1 = pb0 + (size_t)16 * K;

  f32x4 acc00 = {0.f, 0.f, 0.f, 0.f};
  f32x4 acc01 = {0.f, 0.f, 0.f, 0.f};
  f32x4 acc10 = {0.f, 0.f, 0.f, 0.f};
  f32x4 acc11 = {0.f, 0.f, 0.f, 0.f};

  for (int kk = 0; kk < K; kk += 32) {
    bf16x8 a0 = *reinterpret_cast<const bf16x8*>(pa0 + kk);
    bf16x8 a1 = *reinterpret_cast<const bf16x8*>(pa1 + kk);
    bf16x8 b0 = *reinterpret_cast<const bf16x8*>(pb0 + kk);
    bf16x8 b1 = *reinterpret_cast<const bf16x8*>(pb1 + kk);
    acc00 = __builtin_amdgcn_mfma_f32_16x16x32_bf16(a0, b0, acc00, 0, 0, 0);
    acc01 = __builtin_amdgcn_mfma_f32_16x16x32_bf16(a0, b1, acc01, 0, 0, 0);
    acc10 = __builtin_amdgcn_mfma_f32_16x16x32_bf16(a1, b0, acc10, 0, 0, 0);
    acc11 = __builtin_amdgcn_mfma_f32_16x16x32_bf16(a1, b1, acc11, 0, 0, 0);
  }

  const int rm_ = (lane >> 4) * 4;
  auto emit = [&](const f32x4& acc, int mt, int nt) {
    const int rm = m0 + mt * 16 + rm_;
    const int cn = n0 + nt * 16 + lr;
    float4 v = {acc[0], acc[1], acc[2], acc[3]};
    if constexpr (BIASM == 1) {
      float bv = bias[cn];
      v.x += bv; v.y += bv; v.z += bv; v.w += bv;
    } else if constexpr (BIASM == 2) {
      float4 b4 = *reinterpret_cast<const float4*>(bias + rm);
      v.x += b4.x; v.y += b4.y; v.z += b4.z; v.w += b4.w;
    }
    const size_t off = (size_t)cn * (size_t)ldc + rm;
    if constexpr (F32OUT) {
      float* C = (float*)Cv + (size_t)b * sC;
      *reinterpret_cast<float4*>(C + off) = v;
    } else {
      ushort* C = (ushort*)Cv + (size_t)b * sC;
      ushort4 u = {f2bf(v.x), f2bf(v.y), f2bf(v.z), f2bf(v.w)};
      *reinterpret_cast<ushort4*>(C + off) = u;
    }
  };
  emit(acc00, 0, 0); emit(acc01, 0, 1); emit(acc10, 1, 0); emit(acc11, 1, 1);
}

// ---------------------------------------------------------------------------
// BN(eval)+ReLU with transpose: src f32 [B,512,1024] -> out bf16 [B,1024,512]
// Handles two tensors (A-side, B-side) via blockIdx.z = b*2 + which.
// ---------------------------------------------------------------------------
__global__ __launch_bounds__(256) void bn_t_k(
    const float* __restrict__ srcA, const float* __restrict__ srcB,
    const float* __restrict__ g, const float* __restrict__ bb,
    const float* __restrict__ mm, const float* __restrict__ vv,
    ushort* __restrict__ outA, ushort* __restrict__ outB)
{
  const int z = blockIdx.z;
  const int b = z >> 1, which = z & 1;
  const float* src = which ? srcB : srcA;
  ushort* out = which ? outB : outA;
  src += (size_t)b * 512 * 1024;
  out += (size_t)b * 1024 * 512;

  __shared__ float tile[32][33];
  const int n0 = blockIdx.x * 32, c0 = blockIdx.y * 32;
  const int tx = threadIdx.x & 31, ty = threadIdx.x >> 5;  // ty 0..7

  #pragma unroll
  for (int i = 0; i < 4; ++i) {
    const int c = c0 + ty + i * 8;
    const float sc = g[c] * rsqrtf(vv[c] + 1e-5f);
    const float sh = bb[c] - mm[c] * sc;
    float x = src[(size_t)c * 1024 + n0 + tx];
    tile[ty + i * 8][tx] = fmaxf(x * sc + sh, 0.f);
  }
  __syncthreads();
  #pragma unroll
  for (int i = 0; i < 4; ++i) {
    const int n = n0 + ty + i * 8;
    out[(size_t)n * 512 + c0 + tx] = f2bf(tile[tx][ty + i * 8]);
  }
}

// ---------------------------------------------------------------------------
// Row softmax: S f32 [rows][1024] -> P bf16 [rows][1024], one row per block.
// ---------------------------------------------------------------------------
__global__ __launch_bounds__(256) void softmax_k(
    const float* __restrict__ S, ushort* __restrict__ Pout)
{
  const size_t row = blockIdx.x;
  const float* r = S + row * 1024;
  const int t = threadIdx.x;
  float4 v = reinterpret_cast<const float4*>(r)[t];
  float mx = fmaxf(fmaxf(v.x, v.y), fmaxf(v.z, v.w));
  #pragma unroll
  for (int o = 32; o >= 1; o >>= 1) mx = fmaxf(mx, __shfl_xor(mx, o, 64));
  __shared__ float smax[4], ssum[4];
  const int wid = t >> 6, lane = t & 63;
  if (lane == 0) smax[wid] = mx;
  __syncthreads();
  mx = fmaxf(fmaxf(smax[0], smax[1]), fmaxf(smax[2], smax[3]));
  float e0 = __expf(v.x - mx), e1 = __expf(v.y - mx);
  float e2 = __expf(v.z - mx), e3 = __expf(v.w - mx);
  float s = e0 + e1 + e2 + e3;
  #pragma unroll
  for (int o = 32; o >= 1; o >>= 1) s += __shfl_xor(s, o, 64);
  if (lane == 0) ssum[wid] = s;
  __syncthreads();
  s = ssum[0] + ssum[1] + ssum[2] + ssum[3];
  const float inv = 1.0f / s;
  ushort4 u = {f2bf(e0 * inv), f2bf(e1 * inv), f2bf(e2 * inv), f2bf(e3 * inv)};
  reinterpret_cast<ushort4*>(Pout + row * 1024)[t] = u;
}

// ---------------------------------------------------------------------------
// Epilogue: out[b][c][n] = relu(src*scale+shift) + WyT[b][c][n]
// (WyT already contains the w_b bias from the GEMM). One (b,c) row per block.
// ---------------------------------------------------------------------------
__global__ __launch_bounds__(256) void epi_k(
    const float* __restrict__ src, const float* __restrict__ WyT,
    const float* __restrict__ g, const float* __restrict__ bb,
    const float* __restrict__ mm, const float* __restrict__ vv,
    float* __restrict__ out)
{
  const int c = blockIdx.x, b = blockIdx.y;
  const float sc = g[c] * rsqrtf(vv[c] + 1e-5f);
  const float sh = bb[c] - mm[c] * sc;
  const size_t base = ((size_t)b * 512 + c) * 1024;
  float4 x = reinterpret_cast<const float4*>(src + base)[threadIdx.x];
  float4 w = reinterpret_cast<const float4*>(WyT + base)[threadIdx.x];
  float4 o;
  o.x = fmaxf(x.x * sc + sh, 0.f) + w.x;
  o.y = fmaxf(x.y * sc + sh, 0.f) + w.y;
  o.z = fmaxf(x.z * sc + sh, 0.f) + w.z;
  o.w = fmaxf(x.w * sc + sh, 0.f) + w.w;
  reinterpret_cast<float4*>(out + base)[threadIdx.x] = o;
}

// f32 -> bf16 weight conversion
__global__ __launch_bounds__(256) void wcvt_k(
    const float* __restrict__ src, ushort* __restrict__ dst, int n)
{
  const int i = blockIdx.x * 256 + threadIdx.x;
  if (i < n) dst[i] = f2bf(src[i]);
}

// ---------------------------------------------------------------------------
// Workspace layout (bytes). Total = 162 MB.
// ---------------------------------------------------------------------------
constexpr size_t OFF_WBF  = 0;                        // 8 * 131072 * 2 = 2 MB
constexpr size_t OFF_ABN  = 0x200000;                 // 16 MB  bf16 [16,1024,512]
constexpr size_t OFF_BBN  = OFF_ABN + 0x1000000;      // 16 MB
constexpr size_t OFF_TH   = OFF_BBN + 0x1000000;      // 8 MB   bf16 [16,1024,256]
constexpr size_t OFF_PH   = OFF_TH  + 0x800000;       // 8 MB
constexpr size_t OFF_GT   = OFF_PH  + 0x800000;       // 8 MB   bf16 [16,256,1024]
constexpr size_t OFF_Y    = OFF_GT  + 0x800000;       // 8 MB   bf16 [16,1024,256]
constexpr size_t OFF_P    = OFF_Y   + 0x800000;       // 32 MB  bf16 [16,1024,1024]
constexpr size_t OFF_ATTN = OFF_P   + 0x2000000;      // 64 MB  f32  [16,1024,1024]
                                                      // (also aliased as WyT f32 32MB)

extern "C" void kernel_launch(void* const* d_in, const int* in_sizes, int n_in,
                              void* d_out, int out_size, void* d_ws, size_t ws_size,
                              hipStream_t stream) {
  const float* rgb  = (const float*)d_in[0];
  const float* flow = (const float*)d_in[1];
  auto in = [&](int mod, int j) { return (const float*)d_in[2 + mod * 12 + j]; };
  // j: 0 bn_g, 1 bn_b, 2 bn_m, 3 bn_v, 4 th_w, 5 th_b, 6 ph_w, 7 ph_b,
  //    8 g_w, 9 g_b, 10 w_w, 11 w_b

  char* ws = (char*)d_ws;
  ushort* wbf  = (ushort*)(ws + OFF_WBF);
  ushort* Abn  = (ushort*)(ws + OFF_ABN);
  ushort* Bbn  = (ushort*)(ws + OFF_BBN);
  ushort* th   = (ushort*)(ws + OFF_TH);
  ushort* ph   = (ushort*)(ws + OFF_PH);
  ushort* gT   = (ushort*)(ws + OFF_GT);
  ushort* yb   = (ushort*)(ws + OFF_Y);
  ushort* Pm   = (ushort*)(ws + OFF_P);
  float*  attn = (float*)(ws + OFF_ATTN);
  float*  WyT  = (float*)(ws + OFF_ATTN);   // alias: attn dead after softmax
  float*  out  = (float*)d_out;

  // Convert all 8 weight matrices (each 131072 elems) to bf16.
  for (int mod = 0; mod < 2; ++mod) {
    const float* srcs[4] = {in(mod, 4), in(mod, 6), in(mod, 8), in(mod, 10)};
    for (int j = 0; j < 4; ++j)
      wcvt_k<<<512, 256, 0, stream>>>(srcs[j], wbf + (size_t)(mod * 4 + j) * 131072, 131072);
  }

  for (int mod = 0; mod < 2; ++mod) {
    const float* As = mod ? flow : rgb;
    const float* Bs = mod ? rgb : flow;
    const ushort* thW = wbf + (size_t)(mod * 4 + 0) * 131072;  // [256,512]
    const ushort* phW = wbf + (size_t)(mod * 4 + 1) * 131072;  // [256,512]
    const ushort* gW  = wbf + (size_t)(mod * 4 + 2) * 131072;  // [256,512]
    const ushort* wW  = wbf + (size_t)(mod * 4 + 3) * 131072;  // [512,256]

    // BN+ReLU+transpose for both operands
    bn_t_k<<<dim3(32, 16, 32), 256, 0, stream>>>(
        As, Bs, in(mod, 0), in(mod, 1), in(mod, 2), in(mod, 3), Abn, Bbn);

    // theta[n][c] = Abn @ th_w^T + th_b   (A=thW, Bt=Abn, trans-store, bias per m')
    gemm_tt<false, 2><<<dim3(4, 16, 16), 256, 0, stream>>>(
        thW, 0, Abn, (size_t)1024 * 512, th, (size_t)1024 * 256, in(mod, 5), 512, 256);
    // phi[n][c]
    gemm_tt<false, 2><<<dim3(4, 16, 16), 256, 0, stream>>>(
        phW, 0, Bbn, (size_t)1024 * 512, ph, (size_t)1024 * 256, in(mod, 7), 512, 256);
    // gT[c][n] = (Abn @ g_w^T + g_b)^T    (A=Abn, Bt=gW, trans-store, bias per n'=c)
    gemm_tt<false, 1><<<dim3(16, 4, 16), 256, 0, stream>>>(
        Abn, (size_t)1024 * 512, gW, 0, gT, (size_t)256 * 1024, in(mod, 9), 512, 1024);
    // attn[n][m] = theta @ phi^T          (A=phi, Bt=theta, trans-store -> f32)
    gemm_tt<true, 0><<<dim3(16, 16, 16), 256, 0, stream>>>(
        ph, (size_t)1024 * 256, th, (size_t)1024 * 256, attn, (size_t)1024 * 1024,
        nullptr, 256, 1024);
    // row softmax -> P bf16
    softmax_k<<<16384, 256, 0, stream>>>(attn, Pm);
    // y[n][c] = P @ g                     (A=gT, Bt=P, trans-store)
    gemm_tt<false, 0><<<dim3(4, 16, 16), 256, 0, stream>>>(
        gT, (size_t)256 * 1024, Pm, (size_t)1024 * 1024, yb, (size_t)1024 * 256,
        nullptr, 1024, 256);
    // WyT[c][n] = (y @ w_w^T + w_b)^T     (A=y, Bt=wW, trans-store f32, bias per n'=c)
    gemm_tt<true, 1><<<dim3(16, 8, 16), 256, 0, stream>>>(
        yb, (size_t)1024 * 256, wW, 0, WyT, (size_t)512 * 1024, in(mod, 11), 256, 1024);
    // out[b][c][n] = bnrelu(src)[c][n] + WyT[c][n]
    epi_k<<<dim3(512, 16), 256, 0, stream>>>(
        As, WyT, in(mod, 0), in(mod, 1), in(mod, 2), in(mod, 3),
        out + (size_t)mod * 16 * 512 * 1024);
  }
}

// Round 2
// 390.070 us; speedup vs baseline: 1.6082x; 1.6082x over previous
//
#include <hip/hip_runtime.h>

// ---------------------------------------------------------------------------
// Mutual Feature Refinement — round 2: flash-fused attention.
// B=16, C=512, CI=256, num=1024. Per module: BN+ReLU -> theta/phi/g proj ->
// flash(QK^T, online softmax, PV) -> W-proj with fused BN-residual epilogue.
// ---------------------------------------------------------------------------

typedef __bf16 bf16x8 __attribute__((ext_vector_type(8)));
typedef float  f32x4  __attribute__((ext_vector_type(4)));
typedef unsigned u32x4 __attribute__((ext_vector_type(4)));
static_assert(sizeof(bf16x8) == 16, "bf16x8 must be 16B");

__device__ __forceinline__ ushort f2bf(float x) {
  unsigned u = __builtin_bit_cast(unsigned, x);
  u = (u + 0x7fffu + ((u >> 16) & 1u)) >> 16;   // RNE
  return (ushort)u;
}
__device__ __forceinline__ unsigned packbf(float lo, float hi) {
  return (unsigned)f2bf(lo) | ((unsigned)f2bf(hi) << 16);
}

// ---------------------------------------------------------------------------
// Generic MFMA GEMM (round-0): D[m'][n'] = sum_k A[m'][k]*Bt[n'][k], stored
// transposed C[n'*ldc+m']. BIASM: 1 = bias per n', 2 = bias per m'.
// ---------------------------------------------------------------------------
template <int BIASM>
__global__ __launch_bounds__(256) void gemm_tt(
    const ushort* __restrict__ A, size_t sA,
    const ushort* __restrict__ Bt, size_t sB,
    ushort* __restrict__ Cv, size_t sC,
    const float* __restrict__ bias,
    int K, int ldc)
{
  const int b = blockIdx.z;
  const ushort* Ab = A + (size_t)b * sA;
  const ushort* Bb = Bt + (size_t)b * sB;
  const int lane = threadIdx.x & 63;
  const int wid  = threadIdx.x >> 6;
  const int m0 = blockIdx.x * 64 + (wid >> 1) * 32;
  const int n0 = blockIdx.y * 64 + (wid & 1) * 32;
  const int lr = lane & 15;
  const int ko = (lane >> 4) * 8;

  const ushort* pa0 = Ab + (size_t)(m0 + lr) * K + ko;
  const ushort* pa1 = pa0 + (size_t)16 * K;
  const ushort* pb0 = Bb + (size_t)(n0 + lr) * K + ko;
  const ushort* pb1 = pb0 + (size_t)16 * K;

  f32x4 acc00 = {0.f,0.f,0.f,0.f}, acc01 = {0.f,0.f,0.f,0.f};
  f32x4 acc10 = {0.f,0.f,0.f,0.f}, acc11 = {0.f,0.f,0.f,0.f};

  for (int kk = 0; kk < K; kk += 32) {
    bf16x8 a0 = *reinterpret_cast<const bf16x8*>(pa0 + kk);
    bf16x8 a1 = *reinterpret_cast<const bf16x8*>(pa1 + kk);
    bf16x8 b0 = *reinterpret_cast<const bf16x8*>(pb0 + kk);
    bf16x8 b1 = *reinterpret_cast<const bf16x8*>(pb1 + kk);
    acc00 = __builtin_amdgcn_mfma_f32_16x16x32_bf16(a0, b0, acc00, 0, 0, 0);
    acc01 = __builtin_amdgcn_mfma_f32_16x16x32_bf16(a0, b1, acc01, 0, 0, 0);
    acc10 = __builtin_amdgcn_mfma_f32_16x16x32_bf16(a1, b0, acc10, 0, 0, 0);
    acc11 = __builtin_amdgcn_mfma_f32_16x16x32_bf16(a1, b1, acc11, 0, 0, 0);
  }

  const int rm_ = (lane >> 4) * 4;
  auto emit = [&](const f32x4& acc, int mt, int nt) {
    const int rm = m0 + mt * 16 + rm_;
    const int cn = n0 + nt * 16 + lr;
    float4 v = {acc[0], acc[1], acc[2], acc[3]};
    if constexpr (BIASM == 1) {
      float bv = bias[cn];
      v.x += bv; v.y += bv; v.z += bv; v.w += bv;
    } else {
      float4 b4 = *reinterpret_cast<const float4*>(bias + rm);
      v.x += b4.x; v.y += b4.y; v.z += b4.z; v.w += b4.w;
    }
    ushort* C = Cv + (size_t)b * sC;
    ushort4 u = {f2bf(v.x), f2bf(v.y), f2bf(v.z), f2bf(v.w)};
    *reinterpret_cast<ushort4*>(C + (size_t)cn * ldc + rm) = u;
  };
  emit(acc00, 0, 0); emit(acc01, 0, 1); emit(acc10, 1, 0); emit(acc11, 1, 1);
}

// ---------------------------------------------------------------------------
// W-projection GEMM with fused BN-residual epilogue.
// out[b][c][n] = relu(src*sc+sh) + (y @ wW^T)[n][c] + wb[c]
// A = yb rows n (K=256), Bt = wW rows c. grid (16, 8, 16).
// ---------------------------------------------------------------------------
__global__ __launch_bounds__(256) void wgemm_epi_k(
    const ushort* __restrict__ yb,   // [16][1024][256] bf16
    const ushort* __restrict__ wW,   // [512][256] bf16
    const float* __restrict__ wb,    // [512]
    const float* __restrict__ src,   // [16][512][1024] f32
    const float* __restrict__ g, const float* __restrict__ bb,
    const float* __restrict__ mm, const float* __restrict__ vv,
    float* __restrict__ out)         // [16][512][1024] f32
{
  const int b = blockIdx.z;
  const ushort* Ab = yb + (size_t)b * 262144;
  const int lane = threadIdx.x & 63;
  const int wid  = threadIdx.x >> 6;
  const int m0 = blockIdx.x * 64 + (wid >> 1) * 32;   // n dim
  const int n0 = blockIdx.y * 64 + (wid & 1) * 32;    // c dim
  const int lr = lane & 15;
  const int ko = (lane >> 4) * 8;

  const ushort* pa0 = Ab + (size_t)(m0 + lr) * 256 + ko;
  const ushort* pa1 = pa0 + 16 * 256;
  const ushort* pb0 = wW + (size_t)(n0 + lr) * 256 + ko;
  const ushort* pb1 = pb0 + 16 * 256;

  f32x4 acc00 = {0.f,0.f,0.f,0.f}, acc01 = {0.f,0.f,0.f,0.f};
  f32x4 acc10 = {0.f,0.f,0.f,0.f}, acc11 = {0.f,0.f,0.f,0.f};

  for (int kk = 0; kk < 256; kk += 32) {
    bf16x8 a0 = *reinterpret_cast<const bf16x8*>(pa0 + kk);
    bf16x8 a1 = *reinterpret_cast<const bf16x8*>(pa1 + kk);
    bf16x8 b0 = *reinterpret_cast<const bf16x8*>(pb0 + kk);
    bf16x8 b1 = *reinterpret_cast<const bf16x8*>(pb1 + kk);
    acc00 = __builtin_amdgcn_mfma_f32_16x16x32_bf16(a0, b0, acc00, 0, 0, 0);
    acc01 = __builtin_amdgcn_mfma_f32_16x16x32_bf16(a0, b1, acc01, 0, 0, 0);
    acc10 = __builtin_amdgcn_mfma_f32_16x16x32_bf16(a1, b0, acc10, 0, 0, 0);
    acc11 = __builtin_amdgcn_mfma_f32_16x16x32_bf16(a1, b1, acc11, 0, 0, 0);
  }

  const int rm_ = (lane >> 4) * 4;
  auto emit = [&](const f32x4& acc, int mt, int nt) {
    const int rm = m0 + mt * 16 + rm_;   // n
    const int cn = n0 + nt * 16 + lr;    // c
    const float sc = g[cn] * rsqrtf(vv[cn] + 1e-5f);
    const float sh = bb[cn] - mm[cn] * sc;
    const float bv = wb[cn];
    const size_t base = ((size_t)b * 512 + cn) * 1024 + rm;
    float4 x = *reinterpret_cast<const float4*>(src + base);
    float4 v;
    v.x = acc[0] + bv + fmaxf(x.x * sc + sh, 0.f);
    v.y = acc[1] + bv + fmaxf(x.y * sc + sh, 0.f);
    v.z = acc[2] + bv + fmaxf(x.z * sc + sh, 0.f);
    v.w = acc[3] + bv + fmaxf(x.w * sc + sh, 0.f);
    *reinterpret_cast<float4*>(out + base) = v;
  };
  emit(acc00, 0, 0); emit(acc01, 0, 1); emit(acc10, 1, 0); emit(acc11, 1, 1);
}

// ---------------------------------------------------------------------------
// Fused dual-BN transpose: each 32x32 tile of rgb (or flow) is read once and
// written as bn1-version and bn2-version, transposed to [n][c] bf16.
// z = b*2 + which (which=0: rgb -> Abn1,Bbn2; which=1: flow -> Bbn1,Abn2)
// ---------------------------------------------------------------------------
__global__ __launch_bounds__(256) void bn2_k(
    const float* __restrict__ rgb, const float* __restrict__ flow,
    const float* __restrict__ g1, const float* __restrict__ b1,
    const float* __restrict__ m1, const float* __restrict__ v1,
    const float* __restrict__ g2, const float* __restrict__ b2,
    const float* __restrict__ m2, const float* __restrict__ v2,
    ushort* __restrict__ Abn1, ushort* __restrict__ Bbn1,
    ushort* __restrict__ Abn2, ushort* __restrict__ Bbn2)
{
  const int z = blockIdx.z;
  const int b = z >> 1, which = z & 1;
  const float* src = which ? flow : rgb;
  ushort* o1 = which ? Bbn1 : Abn1;
  ushort* o2 = which ? Abn2 : Bbn2;
  src += (size_t)b * 512 * 1024;
  o1  += (size_t)b * 1024 * 512;
  o2  += (size_t)b * 1024 * 512;

  __shared__ float tile[32][33];
  const int n0 = blockIdx.x * 32, c0 = blockIdx.y * 32;
  const int tx = threadIdx.x & 31, ty = threadIdx.x >> 5;  // ty 0..7

  #pragma unroll
  for (int i = 0; i < 4; ++i) {
    const int c = c0 + ty + i * 8;
    tile[ty + i * 8][tx] = src[(size_t)c * 1024 + n0 + tx];
  }
  __syncthreads();
  const int c = c0 + tx;
  const float s1 = g1[c] * rsqrtf(v1[c] + 1e-5f);
  const float h1 = b1[c] - m1[c] * s1;
  const float s2 = g2[c] * rsqrtf(v2[c] + 1e-5f);
  const float h2 = b2[c] - m2[c] * s2;
  #pragma unroll
  for (int i = 0; i < 4; ++i) {
    const int n = n0 + ty + i * 8;
    const float x = tile[tx][ty + i * 8];
    o1[(size_t)n * 512 + c] = f2bf(fmaxf(x * s1 + h1, 0.f));
    o2[(size_t)n * 512 + c] = f2bf(fmaxf(x * s2 + h2, 0.f));
  }
}

// ---------------------------------------------------------------------------
// Flash attention: per z-instance (mod*16+b): Q=theta [1024][256],
// K=phi [1024][256], Vt=gT [256][1024], out O [1024][256] bf16.
// 4 waves x 32 q-rows (QB=128), KVBLK=32, swapped QK^T (mfma(K,Q)) so
// softmax stats are per-lane; P goes to PV B-operand via 8 bpermutes.
// grid (8, 32), block 256.
// ---------------------------------------------------------------------------
__global__ __launch_bounds__(256, 1) void flash_k(
    const ushort* __restrict__ Qp, const ushort* __restrict__ Kp,
    const ushort* __restrict__ Vp, ushort* __restrict__ Op)
{
  __shared__ __align__(16) ushort Klds[32 * 264];   // 32 rows x 256 (+8 pad)
  __shared__ __align__(16) ushort Vlds[256 * 40];   // 256 rows x 32 (+8 pad)

  const int zb = blockIdx.y;
  const int tid = threadIdx.x;
  const int w = tid >> 6, lane = tid & 63;
  const int q = lane >> 4, lm = lane & 15;

  const ushort* Q = Qp + (size_t)zb * 262144;
  const ushort* K = Kp + (size_t)zb * 262144;
  const ushort* V = Vp + (size_t)zb * 262144;
  ushort*       O = Op + (size_t)zb * 262144;

  const int nrow0 = blockIdx.x * 128 + w * 32;

  // Q fragments (B-operand layout: row = lm, k = q*8 + ...), held in regs.
  bf16x8 qf[2][8];
  #pragma unroll
  for (int nt = 0; nt < 2; ++nt)
    #pragma unroll
    for (int cs = 0; cs < 8; ++cs)
      qf[nt][cs] = *reinterpret_cast<const bf16x8*>(
          Q + (size_t)(nrow0 + nt * 16 + lm) * 256 + cs * 32 + q * 8);

  f32x4 acc[2][16];
  #pragma unroll
  for (int nt = 0; nt < 2; ++nt)
    #pragma unroll
    for (int ct = 0; ct < 16; ++ct)
      acc[nt][ct] = (f32x4){0.f, 0.f, 0.f, 0.f};

  float run_m[2] = {-__builtin_inff(), -__builtin_inff()};
  float run_l[2] = {0.f, 0.f};

  // staging register buffers + index precompute
  bf16x8 kst[4], vst[4];
  int kr[4], kc[4], vr[4], vc[4];
  #pragma unroll
  for (int i = 0; i < 4; ++i) {
    int idx = i * 256 + tid;
    kr[i] = idx >> 5; kc[i] = idx & 31;   // K: 32 rows x 32 chunks
    vr[i] = idx >> 2; vc[i] = idx & 3;    // V: 256 rows x 4 chunks
  }
  auto stage_load = [&](int m0) {
    #pragma unroll
    for (int i = 0; i < 4; ++i)
      kst[i] = *reinterpret_cast<const bf16x8*>(
          K + (size_t)(m0 + kr[i]) * 256 + kc[i] * 8);
    #pragma unroll
    for (int i = 0; i < 4; ++i)
      vst[i] = *reinterpret_cast<const bf16x8*>(
          V + (size_t)vr[i] * 1024 + m0 + vc[i] * 8);
  };

  stage_load(0);

  for (int t = 0; t < 32; ++t) {
    __syncthreads();   // previous tile's compute done reading LDS
    #pragma unroll
    for (int i = 0; i < 4; ++i)
      *reinterpret_cast<bf16x8*>(Klds + kr[i] * 264 + kc[i] * 8) = kst[i];
    #pragma unroll
    for (int i = 0; i < 4; ++i)
      *reinterpret_cast<bf16x8*>(Vlds + vr[i] * 40 + vc[i] * 8) = vst[i];
    __syncthreads();   // tile ready
    if (t < 31) stage_load((t + 1) * 32);

    // ---- QK^T (swapped: A=K rows m, B=Q rows n) -> s[nt][mt]
    f32x4 s[2][2];
    s[0][0] = s[0][1] = s[1][0] = s[1][1] = (f32x4){0.f, 0.f, 0.f, 0.f};
    #pragma unroll
    for (int cs = 0; cs < 8; ++cs) {
      bf16x8 k0 = *reinterpret_cast<const bf16x8*>(Klds + lm * 264 + cs * 32 + q * 8);
      bf16x8 k1 = *reinterpret_cast<const bf16x8*>(Klds + (16 + lm) * 264 + cs * 32 + q * 8);
      s[0][0] = __builtin_amdgcn_mfma_f32_16x16x32_bf16(k0, qf[0][cs], s[0][0], 0, 0, 0);
      s[1][0] = __builtin_amdgcn_mfma_f32_16x16x32_bf16(k0, qf[1][cs], s[1][0], 0, 0, 0);
      s[0][1] = __builtin_amdgcn_mfma_f32_16x16x32_bf16(k1, qf[0][cs], s[0][1], 0, 0, 0);
      s[1][1] = __builtin_amdgcn_mfma_f32_16x16x32_bf16(k1, qf[1][cs], s[1][1], 0, 0, 0);
    }
    // lane holds S[m = mt*16 + q*4 + j][n = nt*16 + lm]

    // ---- online softmax (stats per row n, per-lane after xor 16/32)
    float mnew[2]; bool cond[2];
    #pragma unroll
    for (int nt = 0; nt < 2; ++nt) {
      float ml = fmaxf(fmaxf(fmaxf(s[nt][0][0], s[nt][0][1]),
                             fmaxf(s[nt][0][2], s[nt][0][3])),
                       fmaxf(fmaxf(s[nt][1][0], s[nt][1][1]),
                             fmaxf(s[nt][1][2], s[nt][1][3])));
      ml = fmaxf(ml, __shfl_xor(ml, 16));
      ml = fmaxf(ml, __shfl_xor(ml, 32));
      cond[nt] = (ml <= run_m[nt] + 8.f);
      mnew[nt] = fmaxf(run_m[nt], ml);
    }
    if (!__all(cond[0] && cond[1])) {   // defer-max: rescale only when needed
      #pragma unroll
      for (int nt = 0; nt < 2; ++nt) {
        float sc = __expf(run_m[nt] - mnew[nt]);
        run_m[nt] = mnew[nt];
        run_l[nt] *= sc;
        #pragma unroll
        for (int ct = 0; ct < 16; ++ct) acc[nt][ct] *= sc;
      }
    }

    bf16x8 pf[2];
    #pragma unroll
    for (int nt = 0; nt < 2; ++nt) {
      float p00 = __expf(s[nt][0][0] - run_m[nt]);
      float p01 = __expf(s[nt][0][1] - run_m[nt]);
      float p02 = __expf(s[nt][0][2] - run_m[nt]);
      float p03 = __expf(s[nt][0][3] - run_m[nt]);
      float p10 = __expf(s[nt][1][0] - run_m[nt]);
      float p11 = __expf(s[nt][1][1] - run_m[nt]);
      float p12 = __expf(s[nt][1][2] - run_m[nt]);
      float p13 = __expf(s[nt][1][3] - run_m[nt]);
      float ts = ((p00 + p01) + (p02 + p03)) + ((p10 + p11) + (p12 + p13));
      ts += __shfl_xor(ts, 16);
      ts += __shfl_xor(ts, 32);
      run_l[nt] += ts;
      // pack to bf16 pairs: u[mt][h] covers m = mt*16 + q*4 + 2h + {0,1}
      unsigned u00 = packbf(p00, p01), u01 = packbf(p02, p03);
      unsigned u10 = packbf(p10, p11), u11 = packbf(p12, p13);
      // redistribute: lane needs P[n=lm(+nt*16)][m = q*8 .. q*8+7]
      const int srclo = (q & 1) * 32 + lm;
      const int srchi = srclo + 16;
      unsigned x00 = (unsigned)__shfl((int)u00, srclo);
      unsigned x10 = (unsigned)__shfl((int)u10, srclo);
      unsigned x01 = (unsigned)__shfl((int)u01, srclo);
      unsigned x11 = (unsigned)__shfl((int)u11, srclo);
      unsigned y00 = (unsigned)__shfl((int)u00, srchi);
      unsigned y10 = (unsigned)__shfl((int)u10, srchi);
      unsigned y01 = (unsigned)__shfl((int)u01, srchi);
      unsigned y11 = (unsigned)__shfl((int)u11, srchi);
      const bool hi = (q >= 2);
      u32x4 wv;
      wv[0] = hi ? x10 : x00;
      wv[1] = hi ? x11 : x01;
      wv[2] = hi ? y10 : y00;
      wv[3] = hi ? y11 : y01;
      pf[nt] = __builtin_bit_cast(bf16x8, wv);
    }

    // ---- PV: acc[nt][ct] += mfma(Vt-frag(c rows), pf[nt])
    #pragma unroll
    for (int ct = 0; ct < 16; ++ct) {
      bf16x8 vf = *reinterpret_cast<const bf16x8*>(
          Vlds + (ct * 16 + lm) * 40 + q * 8);
      acc[0][ct] = __builtin_amdgcn_mfma_f32_16x16x32_bf16(vf, pf[0], acc[0][ct], 0, 0, 0);
      acc[1][ct] = __builtin_amdgcn_mfma_f32_16x16x32_bf16(vf, pf[1], acc[1][ct], 0, 0, 0);
    }
  }

  // ---- epilogue: normalize and store O[n][c] bf16
  #pragma unroll
  for (int nt = 0; nt < 2; ++nt) {
    const float inv = 1.f / run_l[nt];
    const int n = nrow0 + nt * 16 + lm;
    #pragma unroll
    for (int ct = 0; ct < 16; ++ct) {
      ushort4 st = {f2bf(acc[nt][ct][0] * inv), f2bf(acc[nt][ct][1] * inv),
                    f2bf(acc[nt][ct][2] * inv), f2bf(acc[nt][ct][3] * inv)};
      *reinterpret_cast<ushort4*>(O + (size_t)n * 256 + ct * 16 + q * 4) = st;
    }
  }
}

// f32 -> bf16 weight conversion
__global__ __launch_bounds__(256) void wcvt_k(
    const float* __restrict__ src, ushort* __restrict__ dst, int n)
{
  const int i = blockIdx.x * 256 + threadIdx.x;
  if (i < n) dst[i] = f2bf(src[i]);
}

// ---------------------------------------------------------------------------
// Workspace layout (bytes). Total = 130 MB.
// ---------------------------------------------------------------------------
constexpr size_t OFF_WBF = 0;                        // 2 MB: [2][4][131072] bf16
constexpr size_t OFF_BN  = 0x200000;                 // 4 x 16 MB: Abn1,Bbn1,Abn2,Bbn2
constexpr size_t OFF_TH  = OFF_BN + 0x4000000;       // 16 MB [2][16][1024][256]
constexpr size_t OFF_PH  = OFF_TH + 0x1000000;       // 16 MB
constexpr size_t OFF_GT  = OFF_PH + 0x1000000;       // 16 MB [2][16][256][1024]
constexpr size_t OFF_YB  = OFF_GT + 0x1000000;       // 16 MB [2][16][1024][256]

extern "C" void kernel_launch(void* const* d_in, const int* in_sizes, int n_in,
                              void* d_out, int out_size, void* d_ws, size_t ws_size,
                              hipStream_t stream) {
  const float* rgb  = (const float*)d_in[0];
  const float* flow = (const float*)d_in[1];
  auto in = [&](int mod, int j) { return (const float*)d_in[2 + mod * 12 + j]; };
  // j: 0 bn_g, 1 bn_b, 2 bn_m, 3 bn_v, 4 th_w, 5 th_b, 6 ph_w, 7 ph_b,
  //    8 g_w, 9 g_b, 10 w_w, 11 w_b

  char* ws = (char*)d_ws;
  ushort* wbf  = (ushort*)(ws + OFF_WBF);
  ushort* Abn1 = (ushort*)(ws + OFF_BN);
  ushort* Bbn1 = (ushort*)(ws + OFF_BN + 0x1000000);
  ushort* Abn2 = (ushort*)(ws + OFF_BN + 0x2000000);
  ushort* Bbn2 = (ushort*)(ws + OFF_BN + 0x3000000);
  ushort* th   = (ushort*)(ws + OFF_TH);
  ushort* ph   = (ushort*)(ws + OFF_PH);
  ushort* gT   = (ushort*)(ws + OFF_GT);
  ushort* yb   = (ushort*)(ws + OFF_YB);
  float*  out  = (float*)d_out;

  // weights -> bf16
  for (int mod = 0; mod < 2; ++mod) {
    const float* srcs[4] = {in(mod, 4), in(mod, 6), in(mod, 8), in(mod, 10)};
    for (int j = 0; j < 4; ++j)
      wcvt_k<<<512, 256, 0, stream>>>(srcs[j], wbf + (size_t)(mod * 4 + j) * 131072, 131072);
  }

  // fused dual-BN transpose (reads rgb+flow once)
  bn2_k<<<dim3(32, 16, 32), 256, 0, stream>>>(
      rgb, flow,
      in(0, 0), in(0, 1), in(0, 2), in(0, 3),
      in(1, 0), in(1, 1), in(1, 2), in(1, 3),
      Abn1, Bbn1, Abn2, Bbn2);

  const size_t MODSTR = (size_t)16 * 262144;   // per-module slice, elements

  for (int mod = 0; mod < 2; ++mod) {
    ushort* Abn = mod ? Abn2 : Abn1;
    ushort* Bbn = mod ? Bbn2 : Bbn1;
    const ushort* thW = wbf + (size_t)(mod * 4 + 0) * 131072;  // [256][512]
    const ushort* phW = wbf + (size_t)(mod * 4 + 1) * 131072;
    const ushort* gW  = wbf + (size_t)(mod * 4 + 2) * 131072;

    // theta[n][c] = Abn @ th_w^T + th_b
    gemm_tt<2><<<dim3(4, 16, 16), 256, 0, stream>>>(
        thW, 0, Abn, (size_t)1024 * 512, th + mod * MODSTR, 262144, in(mod, 5), 512, 256);
    // phi[n][c] = Bbn @ ph_w^T + ph_b
    gemm_tt<2><<<dim3(4, 16, 16), 256, 0, stream>>>(
        phW, 0, Bbn, (size_t)1024 * 512, ph + mod * MODSTR, 262144, in(mod, 7), 512, 256);
    // gT[c][n] = (Abn @ g_w^T + g_b)^T
    gemm_tt<1><<<dim3(16, 4, 16), 256, 0, stream>>>(
        Abn, (size_t)1024 * 512, gW, 0, gT + mod * MODSTR, 262144, in(mod, 9), 512, 1024);
  }

  // flash attention, both modules in one launch (32 instances x 8 q-blocks)
  flash_k<<<dim3(8, 32), 256, 0, stream>>>(th, ph, gT, yb);

  for (int mod = 0; mod < 2; ++mod) {
    const ushort* wW = wbf + (size_t)(mod * 4 + 3) * 131072;   // [512][256]
    const float* As = mod ? flow : rgb;
    wgemm_epi_k<<<dim3(16, 8, 16), 256, 0, stream>>>(
        yb + mod * MODSTR, wW, in(mod, 11), As,
        in(mod, 0), in(mod, 1), in(mod, 2), in(mod, 3),
        out + (size_t)mod * 16 * 512 * 1024);
  }
}

// Round 3
// 255.039 us; speedup vs baseline: 2.4597x; 1.5295x over previous
//
#include <hip/hip_runtime.h>

// ---------------------------------------------------------------------------
// Mutual Feature Refinement — round 3.
// B=16, C=512, CI=256, num=1024.
// Pipeline: wcvt(1) -> bn2(1) -> proj128(1, all 6 projections, LDS-staged)
//           -> flash (KV-split x2, 512 blocks, XCD-chunked) -> merge
//           -> wgemm_epi x2.
// ---------------------------------------------------------------------------

typedef __bf16 bf16x8 __attribute__((ext_vector_type(8)));
typedef float  f32x4  __attribute__((ext_vector_type(4)));
static_assert(sizeof(bf16x8) == 16, "bf16x8 must be 16B");

__device__ __forceinline__ ushort f2bf(float x) {
  unsigned u = __builtin_bit_cast(unsigned, x);
  u = (u + 0x7fffu + ((u >> 16) & 1u)) >> 16;   // RNE
  return (ushort)u;
}
__device__ __forceinline__ unsigned packbf(float lo, float hi) {
  return (unsigned)f2bf(lo) | ((unsigned)f2bf(hi) << 16);
}

// ---------------------------------------------------------------------------
// Weight conversion: 8 matrices of 131072 f32 -> bf16, one launch.
// ---------------------------------------------------------------------------
struct WcvtArgs { const float* src[8]; };
__global__ __launch_bounds__(256) void wcvt8_k(WcvtArgs a, ushort* __restrict__ dst) {
  const int which = blockIdx.y;
  const int i = blockIdx.x * 256 + threadIdx.x;
  dst[(size_t)which * 131072 + i] = f2bf(a.src[which][i]);
}

// ---------------------------------------------------------------------------
// Fused dual-BN transpose: each 32x32 tile of rgb/flow read once, written as
// bn1- and bn2-normalized bf16, transposed to [n][c].
// ---------------------------------------------------------------------------
__global__ __launch_bounds__(256) void bn2_k(
    const float* __restrict__ rgb, const float* __restrict__ flow,
    const float* __restrict__ g1, const float* __restrict__ b1,
    const float* __restrict__ m1, const float* __restrict__ v1,
    const float* __restrict__ g2, const float* __restrict__ b2,
    const float* __restrict__ m2, const float* __restrict__ v2,
    ushort* __restrict__ Abn1, ushort* __restrict__ Bbn1,
    ushort* __restrict__ Abn2, ushort* __restrict__ Bbn2)
{
  const int z = blockIdx.z;
  const int b = z >> 1, which = z & 1;
  const float* src = which ? flow : rgb;
  ushort* o1 = which ? Bbn1 : Abn1;
  ushort* o2 = which ? Abn2 : Bbn2;
  src += (size_t)b * 512 * 1024;
  o1  += (size_t)b * 1024 * 512;
  o2  += (size_t)b * 1024 * 512;

  __shared__ float tile[32][33];
  const int n0 = blockIdx.x * 32, c0 = blockIdx.y * 32;
  const int tx = threadIdx.x & 31, ty = threadIdx.x >> 5;  // ty 0..7

  #pragma unroll
  for (int i = 0; i < 4; ++i) {
    const int c = c0 + ty + i * 8;
    tile[ty + i * 8][tx] = src[(size_t)c * 1024 + n0 + tx];
  }
  __syncthreads();
  const int c = c0 + tx;
  const float s1 = g1[c] * rsqrtf(v1[c] + 1e-5f);
  const float h1 = b1[c] - m1[c] * s1;
  const float s2 = g2[c] * rsqrtf(v2[c] + 1e-5f);
  const float h2 = b2[c] - m2[c] * s2;
  #pragma unroll
  for (int i = 0; i < 4; ++i) {
    const int n = n0 + ty + i * 8;
    const float x = tile[tx][ty + i * 8];
    o1[(size_t)n * 512 + c] = f2bf(fmaxf(x * s1 + h1, 0.f));
    o2[(size_t)n * 512 + c] = f2bf(fmaxf(x * s2 + h2, 0.f));
  }
}

// ---------------------------------------------------------------------------
// Unified projection GEMM, 128x128 tile, LDS-staged, one launch for all 6.
// D[m][n] = sum_k W[m][k] * act[n][k]; M=256, N=1024, K=512.
// mode 0: out[n*256+m] bf16 + bias[m]  (theta/phi)
// mode 1: out[m*1024+n] bf16 + bias[m] (g, transposed store)
// grid (16, 96): bx -> (mb 2, nb 8); by -> (desc 6, inst 16).
// ---------------------------------------------------------------------------
struct ProjDesc { const ushort* W; const ushort* act; const float* bias;
                  ushort* out; int mode; };
struct ProjArgs { ProjDesc d[6]; };

__global__ __launch_bounds__(256, 2) void proj128_k(ProjArgs pa) {
  __shared__ __align__(16) ushort Al[128 * 80];
  __shared__ __align__(16) ushort Bl[128 * 80];

  const int bx = blockIdx.x;
  const int mb = bx >> 3, nb = bx & 7;
  const int by = blockIdx.y;
  const ProjDesc d = pa.d[by >> 4];
  const int inst = by & 15;
  const ushort* A = d.W;
  const ushort* Bact = d.act + (size_t)inst * 524288;

  const int tid = threadIdx.x;
  const int w = tid >> 6, lane = tid & 63;
  const int q = lane >> 4, lm = lane & 15;
  const int m0 = mb * 128, n0 = nb * 128;

  int row[4], c8[4];
  #pragma unroll
  for (int i = 0; i < 4; ++i) { int g = i * 256 + tid; row[i] = g >> 3; c8[i] = g & 7; }

  bf16x8 ast[4], bst[4];
  auto sload = [&](int kk) {
    #pragma unroll
    for (int i = 0; i < 4; ++i) {
      ast[i] = *reinterpret_cast<const bf16x8*>(A + (size_t)(m0 + row[i]) * 512 + kk + c8[i] * 8);
      bst[i] = *reinterpret_cast<const bf16x8*>(Bact + (size_t)(n0 + row[i]) * 512 + kk + c8[i] * 8);
    }
  };
  sload(0);

  f32x4 acc[4][4];
  #pragma unroll
  for (int i = 0; i < 4; ++i)
    #pragma unroll
    for (int j = 0; j < 4; ++j) acc[i][j] = (f32x4){0.f, 0.f, 0.f, 0.f};

  const int wm = (w >> 1) * 64, wn = (w & 1) * 64;

  for (int t = 0; t < 8; ++t) {
    __syncthreads();
    #pragma unroll
    for (int i = 0; i < 4; ++i) {
      *reinterpret_cast<bf16x8*>(Al + row[i] * 80 + c8[i] * 8) = ast[i];
      *reinterpret_cast<bf16x8*>(Bl + row[i] * 80 + c8[i] * 8) = bst[i];
    }
    __syncthreads();
    if (t < 7) sload((t + 1) * 64);
    #pragma unroll
    for (int ks = 0; ks < 2; ++ks) {
      bf16x8 af[4], bfr[4];
      #pragma unroll
      for (int f = 0; f < 4; ++f)
        af[f] = *reinterpret_cast<const bf16x8*>(Al + (wm + f * 16 + lm) * 80 + ks * 32 + q * 8);
      #pragma unroll
      for (int f = 0; f < 4; ++f)
        bfr[f] = *reinterpret_cast<const bf16x8*>(Bl + (wn + f * 16 + lm) * 80 + ks * 32 + q * 8);
      __builtin_amdgcn_s_setprio(1);
      #pragma unroll
      for (int fi = 0; fi < 4; ++fi)
        #pragma unroll
        for (int fj = 0; fj < 4; ++fj)
          acc[fi][fj] = __builtin_amdgcn_mfma_f32_16x16x32_bf16(af[fi], bfr[fj], acc[fi][fj], 0, 0, 0);
      __builtin_amdgcn_s_setprio(0);
    }
  }

  if (d.mode == 0) {
    ushort* out = d.out + (size_t)inst * 262144;
    #pragma unroll
    for (int fi = 0; fi < 4; ++fi)
      #pragma unroll
      for (int fj = 0; fj < 4; ++fj) {
        const int m4 = m0 + wm + fi * 16 + q * 4;
        const int n  = n0 + wn + fj * 16 + lm;
        float4 bi = *reinterpret_cast<const float4*>(d.bias + m4);
        ushort4 u = {f2bf(acc[fi][fj][0] + bi.x), f2bf(acc[fi][fj][1] + bi.y),
                     f2bf(acc[fi][fj][2] + bi.z), f2bf(acc[fi][fj][3] + bi.w)};
        *reinterpret_cast<ushort4*>(out + (size_t)n * 256 + m4) = u;
      }
  } else {
    ushort* out = d.out + (size_t)inst * 262144;
    #pragma unroll
    for (int fi = 0; fi < 4; ++fi)
      #pragma unroll
      for (int fj = 0; fj < 4; ++fj) {
        const int n = n0 + wn + fj * 16 + lm;
        #pragma unroll
        for (int j = 0; j < 4; ++j) {
          const int m = m0 + wm + fi * 16 + q * 4 + j;
          out[(size_t)m * 1024 + n] = f2bf(acc[fi][fj][j] + d.bias[m]);
        }
      }
  }
}

// ---------------------------------------------------------------------------
// Flash attention, KV-split x2 with f32 partials.
// Per (inst, qb, half): Q rows [qb*128, +128), KV range [half*512, +512).
// 4 waves x 32 q-rows; swapped QK^T; P redistributed via per-wave LDS
// (4x b64 write + 2x b128 read instead of 16 shuffles).
// 1D grid 512, XCD-chunked: each XCD owns 4 instances (KV set = 4MB = L2).
// ---------------------------------------------------------------------------
__global__ __launch_bounds__(256, 2) void flash_k(
    const ushort* __restrict__ Qp, const ushort* __restrict__ Kp,
    const ushort* __restrict__ Vp, float* __restrict__ pO,
    float2* __restrict__ st)
{
  __shared__ __align__(16) ushort Klds[32 * 264];    // 32 kv x 256 (+8 pad)
  __shared__ __align__(16) ushort Vlds[256 * 40];    // 256 c x 32 kv (+8 pad)
  __shared__ __align__(16) ushort Plds[4 * 32 * 40]; // per-wave: 32 n x 32 m (+8)

  const int raw = blockIdx.x;
  const int xcd = raw & 7, loc = raw >> 3;
  const int inst = xcd * 4 + (loc >> 4);
  const int rest = loc & 15;
  const int qb = rest >> 1, half = rest & 1;

  const int tid = threadIdx.x;
  const int w = tid >> 6, lane = tid & 63;
  const int q = lane >> 4, lm = lane & 15;

  const ushort* Q = Qp + (size_t)inst * 262144;
  const ushort* K = Kp + (size_t)inst * 262144;
  const ushort* V = Vp + (size_t)inst * 262144;

  const int nrow0 = qb * 128 + w * 32;
  ushort* Pw = Plds + w * 32 * 40;

  bf16x8 qf[2][8];
  #pragma unroll
  for (int nt = 0; nt < 2; ++nt)
    #pragma unroll
    for (int cs = 0; cs < 8; ++cs)
      qf[nt][cs] = *reinterpret_cast<const bf16x8*>(
          Q + (size_t)(nrow0 + nt * 16 + lm) * 256 + cs * 32 + q * 8);

  f32x4 acc[2][16];
  #pragma unroll
  for (int nt = 0; nt < 2; ++nt)
    #pragma unroll
    for (int ct = 0; ct < 16; ++ct) acc[nt][ct] = (f32x4){0.f, 0.f, 0.f, 0.f};

  float run_m[2] = {-__builtin_inff(), -__builtin_inff()};
  float run_l[2] = {0.f, 0.f};

  int kr[4], kc[4], vr[4], vc[4];
  #pragma unroll
  for (int i = 0; i < 4; ++i) {
    int idx = i * 256 + tid;
    kr[i] = idx >> 5; kc[i] = idx & 31;   // K tile: 32 rows x 32 granules
    vr[i] = idx >> 2; vc[i] = idx & 3;    // V tile: 256 rows x 4 granules
  }
  bf16x8 kst[4], vst[4];
  auto stage_load = [&](int m0) {
    #pragma unroll
    for (int i = 0; i < 4; ++i)
      kst[i] = *reinterpret_cast<const bf16x8*>(K + (size_t)(m0 + kr[i]) * 256 + kc[i] * 8);
    #pragma unroll
    for (int i = 0; i < 4; ++i)
      vst[i] = *reinterpret_cast<const bf16x8*>(V + (size_t)vr[i] * 1024 + m0 + vc[i] * 8);
  };

  const int kvbase = half * 512;
  stage_load(kvbase);

  for (int t = 0; t < 16; ++t) {
    __syncthreads();
    #pragma unroll
    for (int i = 0; i < 4; ++i)
      *reinterpret_cast<bf16x8*>(Klds + kr[i] * 264 + kc[i] * 8) = kst[i];
    #pragma unroll
    for (int i = 0; i < 4; ++i)
      *reinterpret_cast<bf16x8*>(Vlds + vr[i] * 40 + vc[i] * 8) = vst[i];
    __syncthreads();
    if (t < 15) stage_load(kvbase + (t + 1) * 32);

    // ---- QK^T (swapped): s[nt][mt], lane holds S[m=mt*16+q*4+j][n=nt*16+lm]
    f32x4 s[2][2];
    s[0][0] = s[0][1] = s[1][0] = s[1][1] = (f32x4){0.f, 0.f, 0.f, 0.f};
    __builtin_amdgcn_s_setprio(1);
    #pragma unroll
    for (int cs = 0; cs < 8; ++cs) {
      bf16x8 k0 = *reinterpret_cast<const bf16x8*>(Klds + lm * 264 + cs * 32 + q * 8);
      bf16x8 k1 = *reinterpret_cast<const bf16x8*>(Klds + (16 + lm) * 264 + cs * 32 + q * 8);
      s[0][0] = __builtin_amdgcn_mfma_f32_16x16x32_bf16(k0, qf[0][cs], s[0][0], 0, 0, 0);
      s[1][0] = __builtin_amdgcn_mfma_f32_16x16x32_bf16(k0, qf[1][cs], s[1][0], 0, 0, 0);
      s[0][1] = __builtin_amdgcn_mfma_f32_16x16x32_bf16(k1, qf[0][cs], s[0][1], 0, 0, 0);
      s[1][1] = __builtin_amdgcn_mfma_f32_16x16x32_bf16(k1, qf[1][cs], s[1][1], 0, 0, 0);
    }
    __builtin_amdgcn_s_setprio(0);

    // ---- online softmax stats
    float mnew[2]; bool cond[2];
    #pragma unroll
    for (int nt = 0; nt < 2; ++nt) {
      float ml = fmaxf(fmaxf(fmaxf(s[nt][0][0], s[nt][0][1]),
                             fmaxf(s[nt][0][2], s[nt][0][3])),
                       fmaxf(fmaxf(s[nt][1][0], s[nt][1][1]),
                             fmaxf(s[nt][1][2], s[nt][1][3])));
      ml = fmaxf(ml, __shfl_xor(ml, 16));
      ml = fmaxf(ml, __shfl_xor(ml, 32));
      cond[nt] = (ml <= run_m[nt] + 8.f);
      mnew[nt] = fmaxf(run_m[nt], ml);
    }
    if (!__all(cond[0] && cond[1])) {
      #pragma unroll
      for (int nt = 0; nt < 2; ++nt) {
        float sc = __expf(run_m[nt] - mnew[nt]);
        run_m[nt] = mnew[nt];
        run_l[nt] *= sc;
        #pragma unroll
        for (int ct = 0; ct < 16; ++ct) acc[nt][ct] *= sc;
      }
    }

    // ---- P = exp(S - m); write to per-wave LDS [n][m], read back as PV frags
    #pragma unroll
    for (int nt = 0; nt < 2; ++nt) {
      float p00 = __expf(s[nt][0][0] - run_m[nt]);
      float p01 = __expf(s[nt][0][1] - run_m[nt]);
      float p02 = __expf(s[nt][0][2] - run_m[nt]);
      float p03 = __expf(s[nt][0][3] - run_m[nt]);
      float p10 = __expf(s[nt][1][0] - run_m[nt]);
      float p11 = __expf(s[nt][1][1] - run_m[nt]);
      float p12 = __expf(s[nt][1][2] - run_m[nt]);
      float p13 = __expf(s[nt][1][3] - run_m[nt]);
      float ts = ((p00 + p01) + (p02 + p03)) + ((p10 + p11) + (p12 + p13));
      ts += __shfl_xor(ts, 16);
      ts += __shfl_xor(ts, 32);
      run_l[nt] += ts;
      uint2 lo = {packbf(p00, p01), packbf(p02, p03)};   // m = q*4+0..3
      uint2 hi = {packbf(p10, p11), packbf(p12, p13)};   // m = 16+q*4+0..3
      *reinterpret_cast<uint2*>(Pw + (nt * 16 + lm) * 40 + q * 4) = lo;
      *reinterpret_cast<uint2*>(Pw + (nt * 16 + lm) * 40 + 16 + q * 4) = hi;
    }
    bf16x8 pf[2];
    #pragma unroll
    for (int nt = 0; nt < 2; ++nt)
      pf[nt] = *reinterpret_cast<const bf16x8*>(Pw + (nt * 16 + lm) * 40 + q * 8);

    // ---- PV
    __builtin_amdgcn_s_setprio(1);
    #pragma unroll
    for (int ct = 0; ct < 16; ++ct) {
      bf16x8 vf = *reinterpret_cast<const bf16x8*>(Vlds + (ct * 16 + lm) * 40 + q * 8);
      acc[0][ct] = __builtin_amdgcn_mfma_f32_16x16x32_bf16(vf, pf[0], acc[0][ct], 0, 0, 0);
      acc[1][ct] = __builtin_amdgcn_mfma_f32_16x16x32_bf16(vf, pf[1], acc[1][ct], 0, 0, 0);
    }
    __builtin_amdgcn_s_setprio(0);
  }

  // ---- store unnormalized partials + stats
  const size_t base = (size_t)(half * 32 + inst) * 1024;
  #pragma unroll
  for (int nt = 0; nt < 2; ++nt) {
    const int n = nrow0 + nt * 16 + lm;
    #pragma unroll
    for (int ct = 0; ct < 16; ++ct) {
      float4 v = {acc[nt][ct][0], acc[nt][ct][1], acc[nt][ct][2], acc[nt][ct][3]};
      *reinterpret_cast<float4*>(pO + (base + n) * 256 + ct * 16 + q * 4) = v;
    }
    if (q == 0) st[base + n] = make_float2(run_m[nt], run_l[nt]);
  }
}

// ---------------------------------------------------------------------------
// Merge the two KV halves: yb = (a0*O0 + a1*O1) / (a0*l0 + a1*l1), bf16.
// grid 8192 x 256: block handles 4 rows x 64 c-quads.
// ---------------------------------------------------------------------------
__global__ __launch_bounds__(256) void merge_k(
    const float* __restrict__ pO, const float2* __restrict__ st,
    ushort* __restrict__ yb)
{
  const size_t row = (size_t)blockIdx.x * 4 + (threadIdx.x >> 6);
  const int c4 = (threadIdx.x & 63) * 4;
  const float2 s0 = st[row], s1 = st[32768 + row];
  const float M = fmaxf(s0.x, s1.x);
  const float a0 = __expf(s0.x - M), a1 = __expf(s1.x - M);
  const float inv = 1.f / (a0 * s0.y + a1 * s1.y);
  const float4 o0 = *reinterpret_cast<const float4*>(pO + row * 256 + c4);
  const float4 o1 = *reinterpret_cast<const float4*>(pO + (size_t)8388608 + row * 256 + c4);
  ushort4 u = {f2bf((a0 * o0.x + a1 * o1.x) * inv), f2bf((a0 * o0.y + a1 * o1.y) * inv),
               f2bf((a0 * o0.z + a1 * o1.z) * inv), f2bf((a0 * o0.w + a1 * o1.w) * inv)};
  *reinterpret_cast<ushort4*>(yb + row * 256 + c4) = u;
}

// ---------------------------------------------------------------------------
// W-projection GEMM with fused BN-residual epilogue (round-2, unchanged).
// out[b][c][n] = relu(src*sc+sh) + (y @ wW^T)[n][c] + wb[c]
// ---------------------------------------------------------------------------
__global__ __launch_bounds__(256) void wgemm_epi_k(
    const ushort* __restrict__ yb, const ushort* __restrict__ wW,
    const float* __restrict__ wb, const float* __restrict__ src,
    const float* __restrict__ g, const float* __restrict__ bb,
    const float* __restrict__ mm, const float* __restrict__ vv,
    float* __restrict__ out)
{
  const int b = blockIdx.z;
  const ushort* Ab = yb + (size_t)b * 262144;
  const int lane = threadIdx.x & 63;
  const int wid  = threadIdx.x >> 6;
  const int m0 = blockIdx.x * 64 + (wid >> 1) * 32;   // n dim
  const int n0 = blockIdx.y * 64 + (wid & 1) * 32;    // c dim
  const int lr = lane & 15;
  const int ko = (lane >> 4) * 8;

  const ushort* pa0 = Ab + (size_t)(m0 + lr) * 256 + ko;
  const ushort* pa1 = pa0 + 16 * 256;
  const ushort* pb0 = wW + (size_t)(n0 + lr) * 256 + ko;
  const ushort* pb1 = pb0 + 16 * 256;

  f32x4 acc00 = {0.f,0.f,0.f,0.f}, acc01 = {0.f,0.f,0.f,0.f};
  f32x4 acc10 = {0.f,0.f,0.f,0.f}, acc11 = {0.f,0.f,0.f,0.f};

  for (int kk = 0; kk < 256; kk += 32) {
    bf16x8 a0 = *reinterpret_cast<const bf16x8*>(pa0 + kk);
    bf16x8 a1 = *reinterpret_cast<const bf16x8*>(pa1 + kk);
    bf16x8 b0 = *reinterpret_cast<const bf16x8*>(pb0 + kk);
    bf16x8 b1 = *reinterpret_cast<const bf16x8*>(pb1 + kk);
    acc00 = __builtin_amdgcn_mfma_f32_16x16x32_bf16(a0, b0, acc00, 0, 0, 0);
    acc01 = __builtin_amdgcn_mfma_f32_16x16x32_bf16(a0, b1, acc01, 0, 0, 0);
    acc10 = __builtin_amdgcn_mfma_f32_16x16x32_bf16(a1, b0, acc10, 0, 0, 0);
    acc11 = __builtin_amdgcn_mfma_f32_16x16x32_bf16(a1, b1, acc11, 0, 0, 0);
  }

  const int rm_ = (lane >> 4) * 4;
  auto emit = [&](const f32x4& acc, int mt, int nt) {
    const int rm = m0 + mt * 16 + rm_;   // n
    const int cn = n0 + nt * 16 + lr;    // c
    const float sc = g[cn] * rsqrtf(vv[cn] + 1e-5f);
    const float sh = bb[cn] - mm[cn] * sc;
    const float bv = wb[cn];
    const size_t base = ((size_t)b * 512 + cn) * 1024 + rm;
    float4 x = *reinterpret_cast<const float4*>(src + base);
    float4 v;
    v.x = acc[0] + bv + fmaxf(x.x * sc + sh, 0.f);
    v.y = acc[1] + bv + fmaxf(x.y * sc + sh, 0.f);
    v.z = acc[2] + bv + fmaxf(x.z * sc + sh, 0.f);
    v.w = acc[3] + bv + fmaxf(x.w * sc + sh, 0.f);
    *reinterpret_cast<float4*>(out + base) = v;
  };
  emit(acc00, 0, 0); emit(acc01, 0, 1); emit(acc10, 1, 0); emit(acc11, 1, 1);
}

// ---------------------------------------------------------------------------
// Workspace layout (bytes), ~136.5 MB. pO aliases the BN region (dead after
// proj128); all kernels are sequential on one stream.
// ---------------------------------------------------------------------------
constexpr size_t MB = 1ull << 20;
constexpr size_t OFF_WBF = 0;          // 2 MB
constexpr size_t OFF_BN  = 2 * MB;     // 64 MB: Abn1/Bbn1/Abn2/Bbn2
constexpr size_t OFF_PO  = 2 * MB;     // 67.1 MB f32 partials (aliases BN)
constexpr size_t OFF_YB  = 72 * MB;    // 16 MB  bf16 [32][1024][256]
constexpr size_t OFF_TH  = 88 * MB;    // 16 MB  bf16 [2][16][1024][256]
constexpr size_t OFF_PH  = 104 * MB;   // 16 MB
constexpr size_t OFF_GT  = 120 * MB;   // 16 MB  bf16 [2][16][256][1024]
constexpr size_t OFF_ST  = 136 * MB;   // 512 KB float2 [2][32][1024]

extern "C" void kernel_launch(void* const* d_in, const int* in_sizes, int n_in,
                              void* d_out, int out_size, void* d_ws, size_t ws_size,
                              hipStream_t stream) {
  const float* rgb  = (const float*)d_in[0];
  const float* flow = (const float*)d_in[1];
  auto in = [&](int mod, int j) { return (const float*)d_in[2 + mod * 12 + j]; };
  // j: 0 bn_g, 1 bn_b, 2 bn_m, 3 bn_v, 4 th_w, 5 th_b, 6 ph_w, 7 ph_b,
  //    8 g_w, 9 g_b, 10 w_w, 11 w_b

  char* ws = (char*)d_ws;
  ushort* wbf  = (ushort*)(ws + OFF_WBF);
  ushort* Abn1 = (ushort*)(ws + OFF_BN);
  ushort* Bbn1 = (ushort*)(ws + OFF_BN + 16 * MB);
  ushort* Abn2 = (ushort*)(ws + OFF_BN + 32 * MB);
  ushort* Bbn2 = (ushort*)(ws + OFF_BN + 48 * MB);
  float*  pO   = (float*)(ws + OFF_PO);
  ushort* yb   = (ushort*)(ws + OFF_YB);
  ushort* th   = (ushort*)(ws + OFF_TH);
  ushort* ph   = (ushort*)(ws + OFF_PH);
  ushort* gT   = (ushort*)(ws + OFF_GT);
  float2* st   = (float2*)(ws + OFF_ST);
  float*  out  = (float*)d_out;

  const size_t MODSTR = (size_t)16 * 262144;

  // 1) weights -> bf16 (one launch)
  WcvtArgs wa;
  for (int mod = 0; mod < 2; ++mod) {
    wa.src[mod * 4 + 0] = in(mod, 4);
    wa.src[mod * 4 + 1] = in(mod, 6);
    wa.src[mod * 4 + 2] = in(mod, 8);
    wa.src[mod * 4 + 3] = in(mod, 10);
  }
  wcvt8_k<<<dim3(512, 8), 256, 0, stream>>>(wa, wbf);

  // 2) fused dual-BN transpose
  bn2_k<<<dim3(32, 16, 32), 256, 0, stream>>>(
      rgb, flow,
      in(0, 0), in(0, 1), in(0, 2), in(0, 3),
      in(1, 0), in(1, 1), in(1, 2), in(1, 3),
      Abn1, Bbn1, Abn2, Bbn2);

  // 3) all six projections, one launch
  ProjArgs pa;
  for (int mod = 0; mod < 2; ++mod) {
    const ushort* wb4 = wbf + (size_t)mod * 4 * 131072;
    ushort* Abn = mod ? Abn2 : Abn1;
    ushort* Bbn = mod ? Bbn2 : Bbn1;
    pa.d[mod * 3 + 0] = {wb4,              Abn, in(mod, 5), th + mod * MODSTR, 0};
    pa.d[mod * 3 + 1] = {wb4 + 131072,     Bbn, in(mod, 7), ph + mod * MODSTR, 0};
    pa.d[mod * 3 + 2] = {wb4 + 2 * 131072, Abn, in(mod, 9), gT + mod * MODSTR, 1};
  }
  proj128_k<<<dim3(16, 96), 256, 0, stream>>>(pa);

  // 4) flash attention (both modules, KV-split x2, XCD-chunked 1D grid)
  flash_k<<<dim3(512), 256, 0, stream>>>(th, ph, gT, pO, st);

  // 5) merge halves -> yb bf16
  merge_k<<<dim3(8192), 256, 0, stream>>>(pO, st, yb);

  // 6) W-projection + BN-residual epilogue
  for (int mod = 0; mod < 2; ++mod) {
    const ushort* wW = wbf + (size_t)(mod * 4 + 3) * 131072;
    const float* As = mod ? flow : rgb;
    wgemm_epi_k<<<dim3(16, 8, 16), 256, 0, stream>>>(
        yb + mod * MODSTR, wW, in(mod, 11), As,
        in(mod, 0), in(mod, 1), in(mod, 2), in(mod, 3),
        out + (size_t)mod * 16 * 512 * 1024);
  }
}

// Round 5
// 238.987 us; speedup vs baseline: 2.6249x; 1.0672x over previous
//
#include <hip/hip_runtime.h>

// ---------------------------------------------------------------------------
// Mutual Feature Refinement — round 5.
// flash_k: 32x32x16 MFMA, transposed LINEAR LDS tiles ([granule][row]) staged
// via global_load_lds (no swizzle anywhere; reads contiguous 16B/lane),
// in-register P via packbf + __shfl_xor(32), in-block KV-split merge.
// ---------------------------------------------------------------------------

typedef __bf16 bf16x8 __attribute__((ext_vector_type(8)));
typedef float  f32x4  __attribute__((ext_vector_type(4)));
typedef float  f32x16 __attribute__((ext_vector_type(16)));
typedef unsigned u32x4 __attribute__((ext_vector_type(4)));
static_assert(sizeof(bf16x8) == 16, "bf16x8 must be 16B");

__device__ __forceinline__ ushort f2bf(float x) {
  unsigned u = __builtin_bit_cast(unsigned, x);
  u = (u + 0x7fffu + ((u >> 16) & 1u)) >> 16;   // RNE
  return (ushort)u;
}
__device__ __forceinline__ unsigned packbf(float lo, float hi) {
  return (unsigned)f2bf(lo) | ((unsigned)f2bf(hi) << 16);
}

__device__ __forceinline__ void gload_lds16(const ushort* g, ushort* l) {
  __builtin_amdgcn_global_load_lds(
      (const __attribute__((address_space(1))) void*)g,
      (__attribute__((address_space(3))) void*)l, 16, 0, 0);
}

// ---------------------------------------------------------------------------
// Weight conversion: 8 matrices of 131072 f32 -> bf16, one launch.
// ---------------------------------------------------------------------------
struct WcvtArgs { const float* src[8]; };
__global__ __launch_bounds__(256) void wcvt8_k(WcvtArgs a, ushort* __restrict__ dst) {
  const int which = blockIdx.y;
  const int i = blockIdx.x * 256 + threadIdx.x;
  dst[(size_t)which * 131072 + i] = f2bf(a.src[which][i]);
}

// ---------------------------------------------------------------------------
// Fused dual-BN transpose: rgb/flow read once, written bn1- and bn2-normalized
// bf16, transposed to [n][c].
// ---------------------------------------------------------------------------
__global__ __launch_bounds__(256) void bn2_k(
    const float* __restrict__ rgb, const float* __restrict__ flow,
    const float* __restrict__ g1, const float* __restrict__ b1,
    const float* __restrict__ m1, const float* __restrict__ v1,
    const float* __restrict__ g2, const float* __restrict__ b2,
    const float* __restrict__ m2, const float* __restrict__ v2,
    ushort* __restrict__ Abn1, ushort* __restrict__ Bbn1,
    ushort* __restrict__ Abn2, ushort* __restrict__ Bbn2)
{
  const int z = blockIdx.z;
  const int b = z >> 1, which = z & 1;
  const float* src = which ? flow : rgb;
  ushort* o1 = which ? Bbn1 : Abn1;
  ushort* o2 = which ? Abn2 : Bbn2;
  src += (size_t)b * 512 * 1024;
  o1  += (size_t)b * 1024 * 512;
  o2  += (size_t)b * 1024 * 512;

  __shared__ float tile[32][33];
  const int n0 = blockIdx.x * 32, c0 = blockIdx.y * 32;
  const int tx = threadIdx.x & 31, ty = threadIdx.x >> 5;  // ty 0..7

  #pragma unroll
  for (int i = 0; i < 4; ++i) {
    const int c = c0 + ty + i * 8;
    tile[ty + i * 8][tx] = src[(size_t)c * 1024 + n0 + tx];
  }
  __syncthreads();
  const int c = c0 + tx;
  const float s1 = g1[c] * rsqrtf(v1[c] + 1e-5f);
  const float h1 = b1[c] - m1[c] * s1;
  const float s2 = g2[c] * rsqrtf(v2[c] + 1e-5f);
  const float h2 = b2[c] - m2[c] * s2;
  #pragma unroll
  for (int i = 0; i < 4; ++i) {
    const int n = n0 + ty + i * 8;
    const float x = tile[tx][ty + i * 8];
    o1[(size_t)n * 512 + c] = f2bf(fmaxf(x * s1 + h1, 0.f));
    o2[(size_t)n * 512 + c] = f2bf(fmaxf(x * s2 + h2, 0.f));
  }
}

// ---------------------------------------------------------------------------
// Unified projection GEMM, 128x128 tile, LDS-staged, one launch for all 6.
// D[m][n] = sum_k W[m][k]*act[n][k]; M=256, N=1024, K=512.
// mode 0: out[n*256+m] bf16 + bias[m]; mode 1: out[m*1024+n] bf16 + bias[m].
// ---------------------------------------------------------------------------
struct ProjDesc { const ushort* W; const ushort* act; const float* bias;
                  ushort* out; int mode; };
struct ProjArgs { ProjDesc d[6]; };

__global__ __launch_bounds__(256, 2) void proj128_k(ProjArgs pa) {
  __shared__ __align__(16) ushort Al[128 * 80];
  __shared__ __align__(16) ushort Bl[128 * 80];

  const int bx = blockIdx.x;
  const int mb = bx >> 3, nb = bx & 7;
  const int by = blockIdx.y;
  const ProjDesc d = pa.d[by >> 4];
  const int inst = by & 15;
  const ushort* A = d.W;
  const ushort* Bact = d.act + (size_t)inst * 524288;

  const int tid = threadIdx.x;
  const int w = tid >> 6, lane = tid & 63;
  const int q = lane >> 4, lm = lane & 15;
  const int m0 = mb * 128, n0 = nb * 128;

  int row[4], c8[4];
  #pragma unroll
  for (int i = 0; i < 4; ++i) { int g = i * 256 + tid; row[i] = g >> 3; c8[i] = g & 7; }

  bf16x8 ast[4], bst[4];
  auto sload = [&](int kk) {
    #pragma unroll
    for (int i = 0; i < 4; ++i) {
      ast[i] = *reinterpret_cast<const bf16x8*>(A + (size_t)(m0 + row[i]) * 512 + kk + c8[i] * 8);
      bst[i] = *reinterpret_cast<const bf16x8*>(Bact + (size_t)(n0 + row[i]) * 512 + kk + c8[i] * 8);
    }
  };
  sload(0);

  f32x4 acc[4][4];
  #pragma unroll
  for (int i = 0; i < 4; ++i)
    #pragma unroll
    for (int j = 0; j < 4; ++j) acc[i][j] = (f32x4){0.f, 0.f, 0.f, 0.f};

  const int wm = (w >> 1) * 64, wn = (w & 1) * 64;

  for (int t = 0; t < 8; ++t) {
    __syncthreads();
    #pragma unroll
    for (int i = 0; i < 4; ++i) {
      *reinterpret_cast<bf16x8*>(Al + row[i] * 80 + c8[i] * 8) = ast[i];
      *reinterpret_cast<bf16x8*>(Bl + row[i] * 80 + c8[i] * 8) = bst[i];
    }
    __syncthreads();
    if (t < 7) sload((t + 1) * 64);
    #pragma unroll
    for (int ks = 0; ks < 2; ++ks) {
      bf16x8 af[4], bfr[4];
      #pragma unroll
      for (int f = 0; f < 4; ++f)
        af[f] = *reinterpret_cast<const bf16x8*>(Al + (wm + f * 16 + lm) * 80 + ks * 32 + q * 8);
      #pragma unroll
      for (int f = 0; f < 4; ++f)
        bfr[f] = *reinterpret_cast<const bf16x8*>(Bl + (wn + f * 16 + lm) * 80 + ks * 32 + q * 8);
      __builtin_amdgcn_s_setprio(1);
      #pragma unroll
      for (int fi = 0; fi < 4; ++fi)
        #pragma unroll
        for (int fj = 0; fj < 4; ++fj)
          acc[fi][fj] = __builtin_amdgcn_mfma_f32_16x16x32_bf16(af[fi], bfr[fj], acc[fi][fj], 0, 0, 0);
      __builtin_amdgcn_s_setprio(0);
    }
  }

  if (d.mode == 0) {
    ushort* out = d.out + (size_t)inst * 262144;
    #pragma unroll
    for (int fi = 0; fi < 4; ++fi)
      #pragma unroll
      for (int fj = 0; fj < 4; ++fj) {
        const int m4 = m0 + wm + fi * 16 + q * 4;
        const int n  = n0 + wn + fj * 16 + lm;
        float4 bi = *reinterpret_cast<const float4*>(d.bias + m4);
        ushort4 u = {f2bf(acc[fi][fj][0] + bi.x), f2bf(acc[fi][fj][1] + bi.y),
                     f2bf(acc[fi][fj][2] + bi.z), f2bf(acc[fi][fj][3] + bi.w)};
        *reinterpret_cast<ushort4*>(out + (size_t)n * 256 + m4) = u;
      }
  } else {
    ushort* out = d.out + (size_t)inst * 262144;
    #pragma unroll
    for (int fi = 0; fi < 4; ++fi)
      #pragma unroll
      for (int fj = 0; fj < 4; ++fj) {
        const int n = n0 + wn + fj * 16 + lm;
        #pragma unroll
        for (int j = 0; j < 4; ++j) {
          const int m = m0 + wm + fi * 16 + q * 4 + j;
          out[(size_t)m * 1024 + n] = f2bf(acc[fi][fj][j] + d.bias[m]);
        }
      }
  }
}

// ---------------------------------------------------------------------------
// Flash attention, 32x32x16 MFMA, in-block KV-split.
// Block: 4 waves. Pairs p=w>>1: p=0 -> kv [0,512), p=1 -> kv [512,1024).
// Wave u=(w&1) owns q-rows [qb*64 + u*32, +32).
// LDS layouts (LINEAR, transposed — no swizzle needed):
//   Klds: [granule g=0..31][kv=0..31] x 8 ushorts   (g = d/8)
//   Vlds: [granule gv=0..3][c=0..255] x 8 ushorts   (gv = kv/8)
// Staged with global_load_lds (dest = base + lane*16; per-lane gather src).
// QK^T swapped (A=K rows kv, B=Q^T) -> S[kv][q=lane&31]; per-lane softmax
// with cross-half __shfl_xor(32); P packed bf16 in-register; PV (A=V^T, B=P).
// Epilogue: pair merge via LDS. grid 512 (XCD-chunked), 256 threads.
// ---------------------------------------------------------------------------
__global__ __launch_bounds__(256, 2) void flash_k(
    const ushort* __restrict__ Qp, const ushort* __restrict__ Kp,
    const ushort* __restrict__ Vp, ushort* __restrict__ Op)
{
  __shared__ __align__(16) ushort KV[2][16384];  // per pair: K 8KB | V 8KB (ushorts)
  __shared__ float2 stat2[2][32];

  const int raw = blockIdx.x;
  const int xcd = raw & 7, loc = raw >> 3;
  const int inst = xcd * 4 + (loc >> 4);   // each XCD owns 4 instances
  const int qb = loc & 15;

  const int tid = threadIdx.x;
  const int w = tid >> 6, lane = tid & 63;
  const int u = w & 1, p = w >> 1;
  const int h = lane >> 5, lm5 = lane & 31;
  const bool hh = (h != 0);

  const ushort* Q = Qp + (size_t)inst * 262144;
  const ushort* K = Kp + (size_t)inst * 262144;
  const ushort* V = Vp + (size_t)inst * 262144;

  ushort* Klds = &KV[p][0];
  ushort* Vlds = &KV[p][8192];

  const int nrow0 = qb * 64 + u * 32;

  // Q fragments (B-operand: col=lm5 -> q-row, k = h*8+e within subtile cs)
  bf16x8 qf[16];
  #pragma unroll
  for (int cs = 0; cs < 16; ++cs)
    qf[cs] = *reinterpret_cast<const bf16x8*>(
        Q + (size_t)(nrow0 + lm5) * 256 + cs * 16 + h * 8);

  f32x16 acc[8];
  #pragma unroll
  for (int cb = 0; cb < 8; ++cb)
    #pragma unroll
    for (int i = 0; i < 16; ++i) acc[cb][i] = 0.f;

  float run_m = -__builtin_inff();
  float run_l = 0.f;

  // Staging: 16 chunks K (1KB each) + 16 chunks V; waves of a pair split 8/8.
  // K chunk cc: LDS rows g = {2cc, 2cc+1}; lane l -> (g = 2cc + l>>5, kv = l&31).
  // V chunk cc: gv = cc>>2, c-block = cc&3; lane l -> (gv, c = (cc&3)*64 + l).
  auto stage = [&](int t) {
    const int tb = p * 512 + t * 32;
    #pragma unroll
    for (int c = 0; c < 8; ++c) {
      const int cc = u * 8 + c;
      gload_lds16(K + (size_t)(tb + lm5) * 256 + (cc * 2 + h) * 8,
                  Klds + cc * 512);
    }
    #pragma unroll
    for (int c = 0; c < 8; ++c) {
      const int cc = u * 8 + c;
      gload_lds16(V + (size_t)((cc & 3) * 64 + lane) * 1024 + tb + (cc >> 2) * 8,
                  Vlds + cc * 512);
    }
  };

  stage(0);
  asm volatile("s_waitcnt vmcnt(0)" ::: "memory");
  __syncthreads();

  for (int t = 0; t < 16; ++t) {
    // ---- QK^T: S[kv=(r&3)+8*(r>>2)+4h][q=lm5]
    f32x16 S;
    #pragma unroll
    for (int i = 0; i < 16; ++i) S[i] = 0.f;
    __builtin_amdgcn_s_setprio(1);
    #pragma unroll
    for (int cs = 0; cs < 16; ++cs) {
      bf16x8 kf = *reinterpret_cast<const bf16x8*>(
          Klds + ((cs * 2 + h) * 32 + lm5) * 8);
      S = __builtin_amdgcn_mfma_f32_32x32x16_bf16(kf, qf[cs], S, 0, 0, 0);
    }
    __builtin_amdgcn_s_setprio(0);

    // ---- online softmax (per-lane stats; cross-half via shfl_xor 32)
    float ml = fmaxf(fmaxf(fmaxf(S[0], S[1]), fmaxf(S[2], S[3])),
                     fmaxf(fmaxf(S[4], S[5]), fmaxf(S[6], S[7])));
    ml = fmaxf(ml, fmaxf(fmaxf(fmaxf(S[8], S[9]), fmaxf(S[10], S[11])),
                         fmaxf(fmaxf(S[12], S[13]), fmaxf(S[14], S[15]))));
    ml = fmaxf(ml, __shfl_xor(ml, 32));
    const float mnew = fmaxf(run_m, ml);
    if (!__all(ml <= run_m + 8.f)) {      // defer-max
      const float sc = __expf(run_m - mnew);
      run_m = mnew;
      run_l *= sc;
      #pragma unroll
      for (int cb = 0; cb < 8; ++cb) acc[cb] *= sc;
    }
    #pragma unroll
    for (int i = 0; i < 16; ++i) S[i] = __expf(S[i] - run_m);
    float ts = ((S[0] + S[1]) + (S[2] + S[3])) + ((S[4] + S[5]) + (S[6] + S[7]));
    ts += ((S[8] + S[9]) + (S[10] + S[11])) + ((S[12] + S[13]) + (S[14] + S[15]));
    ts += __shfl_xor(ts, 32);
    run_l += ts;

    // ---- pack P to bf16 pairs; partner values via shfl_xor 32
    const unsigned pk0 = packbf(S[0], S[1]),   pk1 = packbf(S[2], S[3]);
    const unsigned pk2 = packbf(S[4], S[5]),   pk3 = packbf(S[6], S[7]);
    const unsigned pk4 = packbf(S[8], S[9]),   pk5 = packbf(S[10], S[11]);
    const unsigned pk6 = packbf(S[12], S[13]), pk7 = packbf(S[14], S[15]);
    const unsigned sx0 = __shfl_xor(pk0, 32), sx1 = __shfl_xor(pk1, 32);
    const unsigned sx2 = __shfl_xor(pk2, 32), sx3 = __shfl_xor(pk3, 32);
    const unsigned sx4 = __shfl_xor(pk4, 32), sx5 = __shfl_xor(pk5, 32);
    const unsigned sx6 = __shfl_xor(pk6, 32), sx7 = __shfl_xor(pk7, 32);
    u32x4 B0, B1;
    B0[0] = hh ? sx2 : pk0;  B0[1] = hh ? sx3 : pk1;
    B0[2] = hh ? pk2 : sx0;  B0[3] = hh ? pk3 : sx1;
    B1[0] = hh ? sx6 : pk4;  B1[1] = hh ? sx7 : pk5;
    B1[2] = hh ? pk6 : sx4;  B1[3] = hh ? pk7 : sx5;
    const bf16x8 pf0 = __builtin_bit_cast(bf16x8, B0);
    const bf16x8 pf1 = __builtin_bit_cast(bf16x8, B1);

    // ---- PV: acc[cb] += V^T(c rows) x P   (v0: kv 0-15, v1: kv 16-31)
    __builtin_amdgcn_s_setprio(1);
    #pragma unroll
    for (int cb = 0; cb < 8; ++cb) {
      bf16x8 v0 = *reinterpret_cast<const bf16x8*>(
          Vlds + ((h * 256) + cb * 32 + lm5) * 8);
      bf16x8 v1 = *reinterpret_cast<const bf16x8*>(
          Vlds + (((2 + h) * 256) + cb * 32 + lm5) * 8);
      acc[cb] = __builtin_amdgcn_mfma_f32_32x32x16_bf16(v0, pf0, acc[cb], 0, 0, 0);
      acc[cb] = __builtin_amdgcn_mfma_f32_32x32x16_bf16(v1, pf1, acc[cb], 0, 0, 0);
    }
    __builtin_amdgcn_s_setprio(0);

    if (t < 15) {
      __syncthreads();
      stage(t + 1);
      asm volatile("s_waitcnt vmcnt(0)" ::: "memory");
      __syncthreads();
    }
  }

  // ---- pair merge (p=1 -> LDS -> p=0 combines) and bf16 store
  __syncthreads();
  if (p == 1 && lane < 32) stat2[u][lm5] = make_float2(run_m, run_l);

  float a0 = 1.f, a1 = 0.f, inv = 1.f;
  float4* mb = reinterpret_cast<float4*>(&KV[0][0]);
  #pragma unroll
  for (int half = 0; half < 2; ++half) {
    __syncthreads();
    if (p == 1) {
      #pragma unroll
      for (int cb2 = 0; cb2 < 4; ++cb2) {
        const int cb = half * 4 + cb2;
        #pragma unroll
        for (int r4 = 0; r4 < 4; ++r4) {
          float4 v = {acc[cb][r4 * 4 + 0], acc[cb][r4 * 4 + 1],
                      acc[cb][r4 * 4 + 2], acc[cb][r4 * 4 + 3]};
          mb[u * 1024 + cb2 * 256 + r4 * 64 + lane] = v;
        }
      }
    }
    __syncthreads();
    if (p == 0) {
      if (half == 0) {
        const float2 s1 = stat2[u][lm5];
        const float M = fmaxf(run_m, s1.x);
        a0 = __expf(run_m - M);
        a1 = __expf(s1.x - M);
        inv = 1.f / (a0 * run_l + a1 * s1.y);
      }
      ushort* Ob = Op + (size_t)inst * 262144 + (size_t)(nrow0 + lm5) * 256;
      #pragma unroll
      for (int cb2 = 0; cb2 < 4; ++cb2) {
        const int cb = half * 4 + cb2;
        #pragma unroll
        for (int r4 = 0; r4 < 4; ++r4) {
          float4 o = mb[u * 1024 + cb2 * 256 + r4 * 64 + lane];
          ushort4 s;
          s.x = f2bf((a0 * acc[cb][r4 * 4 + 0] + a1 * o.x) * inv);
          s.y = f2bf((a0 * acc[cb][r4 * 4 + 1] + a1 * o.y) * inv);
          s.z = f2bf((a0 * acc[cb][r4 * 4 + 2] + a1 * o.z) * inv);
          s.w = f2bf((a0 * acc[cb][r4 * 4 + 3] + a1 * o.w) * inv);
          *reinterpret_cast<ushort4*>(Ob + cb * 32 + r4 * 8 + h * 4) = s;
        }
      }
    }
  }
}

// ---------------------------------------------------------------------------
// W-projection GEMM with fused BN-residual epilogue.
// out[b][c][n] = relu(src*sc+sh) + (y @ wW^T)[n][c] + wb[c]
// ---------------------------------------------------------------------------
__global__ __launch_bounds__(256) void wgemm_epi_k(
    const ushort* __restrict__ yb, const ushort* __restrict__ wW,
    const float* __restrict__ wb, const float* __restrict__ src,
    const float* __restrict__ g, const float* __restrict__ bb,
    const float* __restrict__ mm, const float* __restrict__ vv,
    float* __restrict__ out)
{
  const int b = blockIdx.z;
  const ushort* Ab = yb + (size_t)b * 262144;
  const int lane = threadIdx.x & 63;
  const int wid  = threadIdx.x >> 6;
  const int m0 = blockIdx.x * 64 + (wid >> 1) * 32;   // n dim
  const int n0 = blockIdx.y * 64 + (wid & 1) * 32;    // c dim
  const int lr = lane & 15;
  const int ko = (lane >> 4) * 8;

  const ushort* pa0 = Ab + (size_t)(m0 + lr) * 256 + ko;
  const ushort* pa1 = pa0 + 16 * 256;
  const ushort* pb0 = wW + (size_t)(n0 + lr) * 256 + ko;
  const ushort* pb1 = pb0 + 16 * 256;

  f32x4 acc00 = {0.f,0.f,0.f,0.f}, acc01 = {0.f,0.f,0.f,0.f};
  f32x4 acc10 = {0.f,0.f,0.f,0.f}, acc11 = {0.f,0.f,0.f,0.f};

  for (int kk = 0; kk < 256; kk += 32) {
    bf16x8 a0 = *reinterpret_cast<const bf16x8*>(pa0 + kk);
    bf16x8 a1 = *reinterpret_cast<const bf16x8*>(pa1 + kk);
    bf16x8 b0 = *reinterpret_cast<const bf16x8*>(pb0 + kk);
    bf16x8 b1 = *reinterpret_cast<const bf16x8*>(pb1 + kk);
    acc00 = __builtin_amdgcn_mfma_f32_16x16x32_bf16(a0, b0, acc00, 0, 0, 0);
    acc01 = __builtin_amdgcn_mfma_f32_16x16x32_bf16(a0, b1, acc01, 0, 0, 0);
    acc10 = __builtin_amdgcn_mfma_f32_16x16x32_bf16(a1, b0, acc10, 0, 0, 0);
    acc11 = __builtin_amdgcn_mfma_f32_16x16x32_bf16(a1, b1, acc11, 0, 0, 0);
  }

  const int rm_ = (lane >> 4) * 4;
  auto emit = [&](const f32x4& acc, int mt, int nt) {
    const int rm = m0 + mt * 16 + rm_;   // n
    const int cn = n0 + nt * 16 + lr;    // c
    const float sc = g[cn] * rsqrtf(vv[cn] + 1e-5f);
    const float sh = bb[cn] - mm[cn] * sc;
    const float bv = wb[cn];
    const size_t base = ((size_t)b * 512 + cn) * 1024 + rm;
    float4 x = *reinterpret_cast<const float4*>(src + base);
    float4 v;
    v.x = acc[0] + bv + fmaxf(x.x * sc + sh, 0.f);
    v.y = acc[1] + bv + fmaxf(x.y * sc + sh, 0.f);
    v.z = acc[2] + bv + fmaxf(x.z * sc + sh, 0.f);
    v.w = acc[3] + bv + fmaxf(x.w * sc + sh, 0.f);
    *reinterpret_cast<float4*>(out + base) = v;
  };
  emit(acc00, 0, 0); emit(acc01, 0, 1); emit(acc10, 1, 0); emit(acc11, 1, 1);
}

// ---------------------------------------------------------------------------
// Workspace layout (bytes), 130 MB.
// ---------------------------------------------------------------------------
constexpr size_t MB = 1ull << 20;
constexpr size_t OFF_WBF = 0;          // 2 MB: [2][4][131072] bf16
constexpr size_t OFF_BN  = 2 * MB;     // 64 MB: Abn1/Bbn1/Abn2/Bbn2
constexpr size_t OFF_TH  = 66 * MB;    // 16 MB [2][16][1024][256]
constexpr size_t OFF_PH  = 82 * MB;    // 16 MB
constexpr size_t OFF_GT  = 98 * MB;    // 16 MB [2][16][256][1024]
constexpr size_t OFF_YB  = 114 * MB;   // 16 MB [2][16][1024][256]

extern "C" void kernel_launch(void* const* d_in, const int* in_sizes, int n_in,
                              void* d_out, int out_size, void* d_ws, size_t ws_size,
                              hipStream_t stream) {
  const float* rgb  = (const float*)d_in[0];
  const float* flow = (const float*)d_in[1];
  auto in = [&](int mod, int j) { return (const float*)d_in[2 + mod * 12 + j]; };
  // j: 0 bn_g, 1 bn_b, 2 bn_m, 3 bn_v, 4 th_w, 5 th_b, 6 ph_w, 7 ph_b,
  //    8 g_w, 9 g_b, 10 w_w, 11 w_b

  char* ws = (char*)d_ws;
  ushort* wbf  = (ushort*)(ws + OFF_WBF);
  ushort* Abn1 = (ushort*)(ws + OFF_BN);
  ushort* Bbn1 = (ushort*)(ws + OFF_BN + 16 * MB);
  ushort* Abn2 = (ushort*)(ws + OFF_BN + 32 * MB);
  ushort* Bbn2 = (ushort*)(ws + OFF_BN + 48 * MB);
  ushort* th   = (ushort*)(ws + OFF_TH);
  ushort* ph   = (ushort*)(ws + OFF_PH);
  ushort* gT   = (ushort*)(ws + OFF_GT);
  ushort* yb   = (ushort*)(ws + OFF_YB);
  float*  out  = (float*)d_out;

  const size_t MODSTR = (size_t)16 * 262144;

  // 1) weights -> bf16
  WcvtArgs wa;
  for (int mod = 0; mod < 2; ++mod) {
    wa.src[mod * 4 + 0] = in(mod, 4);
    wa.src[mod * 4 + 1] = in(mod, 6);
    wa.src[mod * 4 + 2] = in(mod, 8);
    wa.src[mod * 4 + 3] = in(mod, 10);
  }
  wcvt8_k<<<dim3(512, 8), 256, 0, stream>>>(wa, wbf);

  // 2) fused dual-BN transpose
  bn2_k<<<dim3(32, 16, 32), 256, 0, stream>>>(
      rgb, flow,
      in(0, 0), in(0, 1), in(0, 2), in(0, 3),
      in(1, 0), in(1, 1), in(1, 2), in(1, 3),
      Abn1, Bbn1, Abn2, Bbn2);

  // 3) all six projections, one launch
  ProjArgs pa;
  for (int mod = 0; mod < 2; ++mod) {
    const ushort* wb4 = wbf + (size_t)mod * 4 * 131072;
    ushort* Abn = mod ? Abn2 : Abn1;
    ushort* Bbn = mod ? Bbn2 : Bbn1;
    pa.d[mod * 3 + 0] = {wb4,              Abn, in(mod, 5), th + mod * MODSTR, 0};
    pa.d[mod * 3 + 1] = {wb4 + 131072,     Bbn, in(mod, 7), ph + mod * MODSTR, 0};
    pa.d[mod * 3 + 2] = {wb4 + 2 * 131072, Abn, in(mod, 9), gT + mod * MODSTR, 1};
  }
  proj128_k<<<dim3(16, 96), 256, 0, stream>>>(pa);

  // 4) flash attention (both modules, in-block KV-split, XCD-chunked)
  flash_k<<<dim3(512), 256, 0, stream>>>(th, ph, gT, yb);

  // 5) W-projection + BN-residual epilogue
  for (int mod = 0; mod < 2; ++mod) {
    const ushort* wW = wbf + (size_t)(mod * 4 + 3) * 131072;
    const float* As = mod ? flow : rgb;
    wgemm_epi_k<<<dim3(16, 8, 16), 256, 0, stream>>>(
        yb + mod * MODSTR, wW, in(mod, 11), As,
        in(mod, 0), in(mod, 1), in(mod, 2), in(mod, 3),
        out + (size_t)mod * 16 * 512 * 1024);
  }
}

// Round 6
// 212.910 us; speedup vs baseline: 2.9464x; 1.1225x over previous
//
#include <hip/hip_runtime.h>

// ---------------------------------------------------------------------------
// Mutual Feature Refinement — round 6.
// flash_k staging rebuilt: phi/g are produced in pre-tiled bank-padded global
// layouts so flash's global_load_lds is a pure linear coalesced copy.
// Counted-vmcnt 3-barrier pipeline (raw s_barrier, no mid-loop full drain).
// Compute core (QK/softmax/PV/merge) identical to round 5 (passing).
// ---------------------------------------------------------------------------

typedef __bf16 bf16x8 __attribute__((ext_vector_type(8)));
typedef float  f32x4  __attribute__((ext_vector_type(4)));
typedef float  f32x16 __attribute__((ext_vector_type(16)));
typedef unsigned u32x4 __attribute__((ext_vector_type(4)));
static_assert(sizeof(bf16x8) == 16, "bf16x8 must be 16B");

// K tile (per 32 kv): 32 rows x 264 ushorts (256 data + 8 pad) = 8704 ushorts.
//   element (kv', d) at ushort 264*kv' + d. Banks: slot16 = 33*kv' + d/8 ->
//   (kv'+chunk)%8 uniform for column reads.
// V tile (per 32 kv): 256 c x 40 ushorts (32 data + 8 pad) = 10240 ushorts.
//   element (c, kv') at ushort c*40 + (kv'>>3)*8 + (kv'&7). Banks:
//   slot16 = 5c + chunk -> (5c+chunk)%8 uniform.
constexpr int KTILE = 8704;    // ushorts
constexpr int VTILE = 10240;   // ushorts
constexpr int KINST = 32 * KTILE;   // 278528
constexpr int VINST = 32 * VTILE;   // 327680

__device__ __forceinline__ ushort f2bf(float x) {
  unsigned u = __builtin_bit_cast(unsigned, x);
  u = (u + 0x7fffu + ((u >> 16) & 1u)) >> 16;   // RNE
  return (ushort)u;
}
__device__ __forceinline__ unsigned packbf(float lo, float hi) {
  return (unsigned)f2bf(lo) | ((unsigned)f2bf(hi) << 16);
}
__device__ __forceinline__ void gload_lds16(const ushort* g, ushort* l) {
  __builtin_amdgcn_global_load_lds(
      (const __attribute__((address_space(1))) void*)g,
      (__attribute__((address_space(3))) void*)l, 16, 0, 0);
}

// ---------------------------------------------------------------------------
// Weight conversion: 8 matrices of 131072 f32 -> bf16, one launch.
// ---------------------------------------------------------------------------
struct WcvtArgs { const float* src[8]; };
__global__ __launch_bounds__(256) void wcvt8_k(WcvtArgs a, ushort* __restrict__ dst) {
  const int which = blockIdx.y;
  const int i = blockIdx.x * 256 + threadIdx.x;
  dst[(size_t)which * 131072 + i] = f2bf(a.src[which][i]);
}

// ---------------------------------------------------------------------------
// Fused dual-BN transpose: rgb/flow read once, written bn1- and bn2-normalized
// bf16, transposed to [n][c].
// ---------------------------------------------------------------------------
__global__ __launch_bounds__(256) void bn2_k(
    const float* __restrict__ rgb, const float* __restrict__ flow,
    const float* __restrict__ g1, const float* __restrict__ b1,
    const float* __restrict__ m1, const float* __restrict__ v1,
    const float* __restrict__ g2, const float* __restrict__ b2,
    const float* __restrict__ m2, const float* __restrict__ v2,
    ushort* __restrict__ Abn1, ushort* __restrict__ Bbn1,
    ushort* __restrict__ Abn2, ushort* __restrict__ Bbn2)
{
  const int z = blockIdx.z;
  const int b = z >> 1, which = z & 1;
  const float* src = which ? flow : rgb;
  ushort* o1 = which ? Bbn1 : Abn1;
  ushort* o2 = which ? Abn2 : Bbn2;
  src += (size_t)b * 512 * 1024;
  o1  += (size_t)b * 1024 * 512;
  o2  += (size_t)b * 1024 * 512;

  __shared__ float tile[32][33];
  const int n0 = blockIdx.x * 32, c0 = blockIdx.y * 32;
  const int tx = threadIdx.x & 31, ty = threadIdx.x >> 5;  // ty 0..7

  #pragma unroll
  for (int i = 0; i < 4; ++i) {
    const int c = c0 + ty + i * 8;
    tile[ty + i * 8][tx] = src[(size_t)c * 1024 + n0 + tx];
  }
  __syncthreads();
  const int c = c0 + tx;
  const float s1 = g1[c] * rsqrtf(v1[c] + 1e-5f);
  const float h1 = b1[c] - m1[c] * s1;
  const float s2 = g2[c] * rsqrtf(v2[c] + 1e-5f);
  const float h2 = b2[c] - m2[c] * s2;
  #pragma unroll
  for (int i = 0; i < 4; ++i) {
    const int n = n0 + ty + i * 8;
    const float x = tile[tx][ty + i * 8];
    o1[(size_t)n * 512 + c] = f2bf(fmaxf(x * s1 + h1, 0.f));
    o2[(size_t)n * 512 + c] = f2bf(fmaxf(x * s2 + h2, 0.f));
  }
}

// ---------------------------------------------------------------------------
// Unified projection GEMM, 128x128 tile, LDS-staged, one launch for all 6.
// D[m][n] = sum_k W[m][k]*act[n][k]; M=256, N=1024, K=512.
// mode 0: theta -> out[n*256+m] bf16 (+bias[m])
// mode 1: phi   -> Kg pre-tiled padded layout (+bias[m])
// mode 2: g     -> Vg pre-tiled padded transposed layout (+bias[m])
// ---------------------------------------------------------------------------
struct ProjDesc { const ushort* W; const ushort* act; const float* bias;
                  ushort* out; int mode; };
struct ProjArgs { ProjDesc d[6]; };

__global__ __launch_bounds__(256, 2) void proj128_k(ProjArgs pa) {
  __shared__ __align__(16) ushort Al[128 * 80];
  __shared__ __align__(16) ushort Bl[128 * 80];

  const int bx = blockIdx.x;
  const int mb = bx >> 3, nb = bx & 7;
  const int by = blockIdx.y;
  const ProjDesc d = pa.d[by >> 4];
  const int inst = by & 15;
  const ushort* A = d.W;
  const ushort* Bact = d.act + (size_t)inst * 524288;

  const int tid = threadIdx.x;
  const int w = tid >> 6, lane = tid & 63;
  const int q = lane >> 4, lm = lane & 15;
  const int m0 = mb * 128, n0 = nb * 128;

  int row[4], c8[4];
  #pragma unroll
  for (int i = 0; i < 4; ++i) { int g = i * 256 + tid; row[i] = g >> 3; c8[i] = g & 7; }

  bf16x8 ast[4], bst[4];
  auto sload = [&](int kk) {
    #pragma unroll
    for (int i = 0; i < 4; ++i) {
      ast[i] = *reinterpret_cast<const bf16x8*>(A + (size_t)(m0 + row[i]) * 512 + kk + c8[i] * 8);
      bst[i] = *reinterpret_cast<const bf16x8*>(Bact + (size_t)(n0 + row[i]) * 512 + kk + c8[i] * 8);
    }
  };
  sload(0);

  f32x4 acc[4][4];
  #pragma unroll
  for (int i = 0; i < 4; ++i)
    #pragma unroll
    for (int j = 0; j < 4; ++j) acc[i][j] = (f32x4){0.f, 0.f, 0.f, 0.f};

  const int wm = (w >> 1) * 64, wn = (w & 1) * 64;

  for (int t = 0; t < 8; ++t) {
    __syncthreads();
    #pragma unroll
    for (int i = 0; i < 4; ++i) {
      *reinterpret_cast<bf16x8*>(Al + row[i] * 80 + c8[i] * 8) = ast[i];
      *reinterpret_cast<bf16x8*>(Bl + row[i] * 80 + c8[i] * 8) = bst[i];
    }
    __syncthreads();
    if (t < 7) sload((t + 1) * 64);
    #pragma unroll
    for (int ks = 0; ks < 2; ++ks) {
      bf16x8 af[4], bfr[4];
      #pragma unroll
      for (int f = 0; f < 4; ++f)
        af[f] = *reinterpret_cast<const bf16x8*>(Al + (wm + f * 16 + lm) * 80 + ks * 32 + q * 8);
      #pragma unroll
      for (int f = 0; f < 4; ++f)
        bfr[f] = *reinterpret_cast<const bf16x8*>(Bl + (wn + f * 16 + lm) * 80 + ks * 32 + q * 8);
      __builtin_amdgcn_s_setprio(1);
      #pragma unroll
      for (int fi = 0; fi < 4; ++fi)
        #pragma unroll
        for (int fj = 0; fj < 4; ++fj)
          acc[fi][fj] = __builtin_amdgcn_mfma_f32_16x16x32_bf16(af[fi], bfr[fj], acc[fi][fj], 0, 0, 0);
      __builtin_amdgcn_s_setprio(0);
    }
  }

  if (d.mode == 0) {
    ushort* out = d.out + (size_t)inst * 262144;
    #pragma unroll
    for (int fi = 0; fi < 4; ++fi)
      #pragma unroll
      for (int fj = 0; fj < 4; ++fj) {
        const int m4 = m0 + wm + fi * 16 + q * 4;
        const int n  = n0 + wn + fj * 16 + lm;
        float4 bi = *reinterpret_cast<const float4*>(d.bias + m4);
        ushort4 u = {f2bf(acc[fi][fj][0] + bi.x), f2bf(acc[fi][fj][1] + bi.y),
                     f2bf(acc[fi][fj][2] + bi.z), f2bf(acc[fi][fj][3] + bi.w)};
        *reinterpret_cast<ushort4*>(out + (size_t)n * 256 + m4) = u;
      }
  } else if (d.mode == 1) {
    // Kg: ushort index = (n>>5)*KTILE + (n&31)*264 + m
    ushort* out = d.out + (size_t)inst * KINST;
    #pragma unroll
    for (int fi = 0; fi < 4; ++fi)
      #pragma unroll
      for (int fj = 0; fj < 4; ++fj) {
        const int m4 = m0 + wm + fi * 16 + q * 4;
        const int n  = n0 + wn + fj * 16 + lm;
        float4 bi = *reinterpret_cast<const float4*>(d.bias + m4);
        ushort4 u = {f2bf(acc[fi][fj][0] + bi.x), f2bf(acc[fi][fj][1] + bi.y),
                     f2bf(acc[fi][fj][2] + bi.z), f2bf(acc[fi][fj][3] + bi.w)};
        *reinterpret_cast<ushort4*>(out + (size_t)(n >> 5) * KTILE + (n & 31) * 264 + m4) = u;
      }
  } else {
    // Vg: ushort index = (n>>5)*VTILE + m*40 + ((n&31)>>3)*8 + (n&7)
    ushort* out = d.out + (size_t)inst * VINST;
    #pragma unroll
    for (int fi = 0; fi < 4; ++fi)
      #pragma unroll
      for (int fj = 0; fj < 4; ++fj) {
        const int n = n0 + wn + fj * 16 + lm;
        const size_t base = (size_t)(n >> 5) * VTILE + ((n & 31) >> 3) * 8 + (n & 7);
        #pragma unroll
        for (int j = 0; j < 4; ++j) {
          const int m = m0 + wm + fi * 16 + q * 4 + j;
          out[base + (size_t)m * 40] = f2bf(acc[fi][fj][j] + d.bias[m]);
        }
      }
  }
}

// ---------------------------------------------------------------------------
// Flash attention, 32x32x16 MFMA, in-block KV-split, pipelined staging.
// Block: 4 waves; pair p = kv half; wave u = q sub-block of 32 rows.
// Klds: 32 rows x 264 ushorts (padded, conflict-free column reads).
// Vlds: 256 c x 40 ushorts (stride-5 slots, conflict-free reads).
// Staging: pure linear global_load_lds from pre-tiled Kg/Vg.
// Pipeline per tile: QK -> vmcnt(0)+bar -> issue K(t+1) -> softmax -> PV
//   -> bar -> issue V(t+1) -> vmcnt(10)+bar.  (raw s_barrier, counted vmcnt)
// ---------------------------------------------------------------------------
__global__ __launch_bounds__(256, 2) void flash_k(
    const ushort* __restrict__ Qp, const ushort* __restrict__ Kg,
    const ushort* __restrict__ Vg, ushort* __restrict__ Op)
{
  __shared__ __align__(16) ushort KV[2][KTILE + VTILE];  // 2 x 37888B
  __shared__ float2 stat2[2][32];

  const int raw = blockIdx.x;
  const int xcd = raw & 7, loc = raw >> 3;
  const int inst = xcd * 4 + (loc >> 4);   // each XCD owns 4 instances
  const int qb = loc & 15;

  const int tid = threadIdx.x;
  const int w = tid >> 6, lane = tid & 63;
  const int u = w & 1, p = w >> 1;
  const int h = lane >> 5, lm5 = lane & 31;

  const ushort* Q  = Qp + (size_t)inst * 262144;
  const ushort* Kt = Kg + (size_t)inst * KINST + (size_t)p * 16 * KTILE;
  const ushort* Vt = Vg + (size_t)inst * VINST + (size_t)p * 16 * VTILE;

  ushort* Klds = &KV[p][0];
  ushort* Vlds = &KV[p][KTILE];

  const int nrow0 = qb * 64 + u * 32;

  // Q fragments (B-operand: col=lm5 -> q-row, k = h*8+e within subtile cs)
  bf16x8 qf[16];
  #pragma unroll
  for (int cs = 0; cs < 16; ++cs)
    qf[cs] = *reinterpret_cast<const bf16x8*>(
        Q + (size_t)(nrow0 + lm5) * 256 + cs * 16 + h * 8);

  f32x16 acc[8];
  #pragma unroll
  for (int cb = 0; cb < 8; ++cb)
    #pragma unroll
    for (int i = 0; i < 16; ++i) acc[cb][i] = 0.f;

  float run_m = -__builtin_inff();
  float run_l = 0.f;

  // K tile = 17 linear chunks of 1KB; wave u=0 does 9, u=1 does 8.
  // V tile = 20 linear chunks; each wave does 10.
  auto stageK = [&](int t) {
    const ushort* src = Kt + (size_t)t * KTILE;
    const int base = u ? 9 : 0;
    #pragma unroll
    for (int j = 0; j < 9; ++j)
      if (u == 0 || j < 8)
        gload_lds16(src + (base + j) * 512 + lane * 8, Klds + (base + j) * 512);
  };
  auto stageV = [&](int t) {
    const ushort* src = Vt + (size_t)t * VTILE;
    #pragma unroll
    for (int j = 0; j < 10; ++j)
      gload_lds16(src + (u * 10 + j) * 512 + lane * 8, Vlds + (u * 10 + j) * 512);
  };

  stageK(0);
  stageV(0);
  asm volatile("s_waitcnt vmcnt(0)" ::: "memory");
  __builtin_amdgcn_sched_barrier(0);
  __builtin_amdgcn_s_barrier();

  for (int t = 0; t < 16; ++t) {
    // ---- QK^T: S[kv=(r&3)+8*(r>>2)+4h][q=lm5]
    f32x16 S;
    #pragma unroll
    for (int i = 0; i < 16; ++i) S[i] = 0.f;
    __builtin_amdgcn_s_setprio(1);
    #pragma unroll
    for (int cs = 0; cs < 16; ++cs) {
      bf16x8 kf = *reinterpret_cast<const bf16x8*>(
          Klds + lm5 * 264 + (cs * 2 + h) * 8);
      S = __builtin_amdgcn_mfma_f32_32x32x16_bf16(kf, qf[cs], S, 0, 0, 0);
    }
    __builtin_amdgcn_s_setprio(0);

    // V(t) has landed (issued last iter; covered by QK); barrier A.
    __builtin_amdgcn_sched_barrier(0);
    asm volatile("s_waitcnt vmcnt(0)" ::: "memory");
    __builtin_amdgcn_sched_barrier(0);
    __builtin_amdgcn_s_barrier();          // A: Klds(t) free, Vlds(t) visible
    __builtin_amdgcn_sched_barrier(0);
    if (t < 15) stageK(t + 1);             // K(t+1) hides under softmax+PV

    // ---- online softmax (per-lane stats; cross-half via shfl_xor 32)
    float ml = fmaxf(fmaxf(fmaxf(S[0], S[1]), fmaxf(S[2], S[3])),
                     fmaxf(fmaxf(S[4], S[5]), fmaxf(S[6], S[7])));
    ml = fmaxf(ml, fmaxf(fmaxf(fmaxf(S[8], S[9]), fmaxf(S[10], S[11])),
                         fmaxf(fmaxf(S[12], S[13]), fmaxf(S[14], S[15]))));
    ml = fmaxf(ml, __shfl_xor(ml, 32));
    const float mnew = fmaxf(run_m, ml);
    if (!__all(ml <= run_m + 8.f)) {      // defer-max
      const float sc = __expf(run_m - mnew);
      run_m = mnew;
      run_l *= sc;
      #pragma unroll
      for (int cb = 0; cb < 8; ++cb) acc[cb] *= sc;
    }
    #pragma unroll
    for (int i = 0; i < 16; ++i) S[i] = __expf(S[i] - run_m);
    float ts = ((S[0] + S[1]) + (S[2] + S[3])) + ((S[4] + S[5]) + (S[6] + S[7]));
    ts += ((S[8] + S[9]) + (S[10] + S[11])) + ((S[12] + S[13]) + (S[14] + S[15]));
    ts += __shfl_xor(ts, 32);
    run_l += ts;

    // ---- pack P to bf16 pairs; partner values via shfl_xor 32
    const unsigned pk0 = packbf(S[0], S[1]),   pk1 = packbf(S[2], S[3]);
    const unsigned pk2 = packbf(S[4], S[5]),   pk3 = packbf(S[6], S[7]);
    const unsigned pk4 = packbf(S[8], S[9]),   pk5 = packbf(S[10], S[11]);
    const unsigned pk6 = packbf(S[12], S[13]), pk7 = packbf(S[14], S[15]);
    const unsigned sx0 = __shfl_xor(pk0, 32), sx1 = __shfl_xor(pk1, 32);
    const unsigned sx2 = __shfl_xor(pk2, 32), sx3 = __shfl_xor(pk3, 32);
    const unsigned sx4 = __shfl_xor(pk4, 32), sx5 = __shfl_xor(pk5, 32);
    const unsigned sx6 = __shfl_xor(pk6, 32), sx7 = __shfl_xor(pk7, 32);
    const bool hh = (h != 0);
    u32x4 B0, B1;
    B0[0] = hh ? sx2 : pk0;  B0[1] = hh ? sx3 : pk1;
    B0[2] = hh ? pk2 : sx0;  B0[3] = hh ? pk3 : sx1;
    B1[0] = hh ? sx6 : pk4;  B1[1] = hh ? sx7 : pk5;
    B1[2] = hh ? pk6 : sx4;  B1[3] = hh ? pk7 : sx5;
    const bf16x8 pf0 = __builtin_bit_cast(bf16x8, B0);
    const bf16x8 pf1 = __builtin_bit_cast(bf16x8, B1);

    // ---- PV: acc[cb] += V^T(c rows) x P   (v0: kv 0-15, v1: kv 16-31)
    __builtin_amdgcn_s_setprio(1);
    #pragma unroll
    for (int cb = 0; cb < 8; ++cb) {
      bf16x8 v0 = *reinterpret_cast<const bf16x8*>(
          Vlds + (cb * 32 + lm5) * 40 + h * 8);
      bf16x8 v1 = *reinterpret_cast<const bf16x8*>(
          Vlds + (cb * 32 + lm5) * 40 + (2 + h) * 8);
      acc[cb] = __builtin_amdgcn_mfma_f32_32x32x16_bf16(v0, pf0, acc[cb], 0, 0, 0);
      acc[cb] = __builtin_amdgcn_mfma_f32_32x32x16_bf16(v1, pf1, acc[cb], 0, 0, 0);
    }
    __builtin_amdgcn_s_setprio(0);

    __builtin_amdgcn_sched_barrier(0);
    __builtin_amdgcn_s_barrier();          // B: Vlds(t) free
    __builtin_amdgcn_sched_barrier(0);
    if (t < 15) {
      stageV(t + 1);                       // V(t+1) hides under next QK
      asm volatile("s_waitcnt vmcnt(10)" ::: "memory");  // K(t+1) done, V in flight
    } else {
      asm volatile("s_waitcnt vmcnt(0)" ::: "memory");
    }
    __builtin_amdgcn_sched_barrier(0);
    __builtin_amdgcn_s_barrier();          // C: Klds(t+1) visible
    __builtin_amdgcn_sched_barrier(0);
  }

  // ---- pair merge (p=1 -> LDS -> p=0 combines) and bf16 store
  __syncthreads();
  if (p == 1 && lane < 32) stat2[u][lm5] = make_float2(run_m, run_l);

  float a0 = 1.f, a1 = 0.f, inv = 1.f;
  float4* mb = reinterpret_cast<float4*>(&KV[0][0]);
  #pragma unroll
  for (int half = 0; half < 2; ++half) {
    __syncthreads();
    if (p == 1) {
      #pragma unroll
      for (int cb2 = 0; cb2 < 4; ++cb2) {
        const int cb = half * 4 + cb2;
        #pragma unroll
        for (int r4 = 0; r4 < 4; ++r4) {
          float4 v = {acc[cb][r4 * 4 + 0], acc[cb][r4 * 4 + 1],
                      acc[cb][r4 * 4 + 2], acc[cb][r4 * 4 + 3]};
          mb[u * 1024 + cb2 * 256 + r4 * 64 + lane] = v;
        }
      }
    }
    __syncthreads();
    if (p == 0) {
      if (half == 0) {
        const float2 s1 = stat2[u][lm5];
        const float M = fmaxf(run_m, s1.x);
        a0 = __expf(run_m - M);
        a1 = __expf(s1.x - M);
        inv = 1.f / (a0 * run_l + a1 * s1.y);
      }
      ushort* Ob = Op + (size_t)inst * 262144 + (size_t)(nrow0 + lm5) * 256;
      #pragma unroll
      for (int cb2 = 0; cb2 < 4; ++cb2) {
        const int cb = half * 4 + cb2;
        #pragma unroll
        for (int r4 = 0; r4 < 4; ++r4) {
          float4 o = mb[u * 1024 + cb2 * 256 + r4 * 64 + lane];
          ushort4 s;
          s.x = f2bf((a0 * acc[cb][r4 * 4 + 0] + a1 * o.x) * inv);
          s.y = f2bf((a0 * acc[cb][r4 * 4 + 1] + a1 * o.y) * inv);
          s.z = f2bf((a0 * acc[cb][r4 * 4 + 2] + a1 * o.z) * inv);
          s.w = f2bf((a0 * acc[cb][r4 * 4 + 3] + a1 * o.w) * inv);
          *reinterpret_cast<ushort4*>(Ob + cb * 32 + r4 * 8 + h * 4) = s;
        }
      }
    }
  }
}

// ---------------------------------------------------------------------------
// W-projection GEMM with fused BN-residual epilogue.
// out[b][c][n] = relu(src*sc+sh) + (y @ wW^T)[n][c] + wb[c]
// ---------------------------------------------------------------------------
__global__ __launch_bounds__(256) void wgemm_epi_k(
    const ushort* __restrict__ yb, const ushort* __restrict__ wW,
    const float* __restrict__ wb, const float* __restrict__ src,
    const float* __restrict__ g, const float* __restrict__ bb,
    const float* __restrict__ mm, const float* __restrict__ vv,
    float* __restrict__ out)
{
  const int b = blockIdx.z;
  const ushort* Ab = yb + (size_t)b * 262144;
  const int lane = threadIdx.x & 63;
  const int wid  = threadIdx.x >> 6;
  const int m0 = blockIdx.x * 64 + (wid >> 1) * 32;   // n dim
  const int n0 = blockIdx.y * 64 + (wid & 1) * 32;    // c dim
  const int lr = lane & 15;
  const int ko = (lane >> 4) * 8;

  const ushort* pa0 = Ab + (size_t)(m0 + lr) * 256 + ko;
  const ushort* pa1 = pa0 + 16 * 256;
  const ushort* pb0 = wW + (size_t)(n0 + lr) * 256 + ko;
  const ushort* pb1 = pb0 + 16 * 256;

  f32x4 acc00 = {0.f,0.f,0.f,0.f}, acc01 = {0.f,0.f,0.f,0.f};
  f32x4 acc10 = {0.f,0.f,0.f,0.f}, acc11 = {0.f,0.f,0.f,0.f};

  for (int kk = 0; kk < 256; kk += 32) {
    bf16x8 a0 = *reinterpret_cast<const bf16x8*>(pa0 + kk);
    bf16x8 a1 = *reinterpret_cast<const bf16x8*>(pa1 + kk);
    bf16x8 b0 = *reinterpret_cast<const bf16x8*>(pb0 + kk);
    bf16x8 b1 = *reinterpret_cast<const bf16x8*>(pb1 + kk);
    acc00 = __builtin_amdgcn_mfma_f32_16x16x32_bf16(a0, b0, acc00, 0, 0, 0);
    acc01 = __builtin_amdgcn_mfma_f32_16x16x32_bf16(a0, b1, acc01, 0, 0, 0);
    acc10 = __builtin_amdgcn_mfma_f32_16x16x32_bf16(a1, b0, acc10, 0, 0, 0);
    acc11 = __builtin_amdgcn_mfma_f32_16x16x32_bf16(a1, b1, acc11, 0, 0, 0);
  }

  const int rm_ = (lane >> 4) * 4;
  auto emit = [&](const f32x4& acc, int mt, int nt) {
    const int rm = m0 + mt * 16 + rm_;   // n
    const int cn = n0 + nt * 16 + lr;    // c
    const float sc = g[cn] * rsqrtf(vv[cn] + 1e-5f);
    const float sh = bb[cn] - mm[cn] * sc;
    const float bv = wb[cn];
    const size_t base = ((size_t)b * 512 + cn) * 1024 + rm;
    float4 x = *reinterpret_cast<const float4*>(src + base);
    float4 v;
    v.x = acc[0] + bv + fmaxf(x.x * sc + sh, 0.f);
    v.y = acc[1] + bv + fmaxf(x.y * sc + sh, 0.f);
    v.z = acc[2] + bv + fmaxf(x.z * sc + sh, 0.f);
    v.w = acc[3] + bv + fmaxf(x.w * sc + sh, 0.f);
    *reinterpret_cast<float4*>(out + base) = v;
  };
  emit(acc00, 0, 0); emit(acc01, 0, 1); emit(acc10, 1, 0); emit(acc11, 1, 1);
}

// ---------------------------------------------------------------------------
// Workspace layout (bytes), ~136 MB.
// ---------------------------------------------------------------------------
constexpr size_t MB = 1ull << 20;
constexpr size_t OFF_WBF = 0;          // 2 MB: [2][4][131072] bf16
constexpr size_t OFF_BN  = 2 * MB;     // 64 MB: Abn1/Bbn1/Abn2/Bbn2
constexpr size_t OFF_TH  = 66 * MB;    // 16 MB [32 inst][1024][256]
constexpr size_t OFF_KG  = 82 * MB;    // 17 MB [32 inst][KINST]
constexpr size_t OFF_VG  = 100 * MB;   // 20 MB [32 inst][VINST]
constexpr size_t OFF_YB  = 120 * MB;   // 16 MB [32 inst][1024][256]

extern "C" void kernel_launch(void* const* d_in, const int* in_sizes, int n_in,
                              void* d_out, int out_size, void* d_ws, size_t ws_size,
                              hipStream_t stream) {
  const float* rgb  = (const float*)d_in[0];
  const float* flow = (const float*)d_in[1];
  auto in = [&](int mod, int j) { return (const float*)d_in[2 + mod * 12 + j]; };
  // j: 0 bn_g, 1 bn_b, 2 bn_m, 3 bn_v, 4 th_w, 5 th_b, 6 ph_w, 7 ph_b,
  //    8 g_w, 9 g_b, 10 w_w, 11 w_b

  char* ws = (char*)d_ws;
  ushort* wbf  = (ushort*)(ws + OFF_WBF);
  ushort* Abn1 = (ushort*)(ws + OFF_BN);
  ushort* Bbn1 = (ushort*)(ws + OFF_BN + 16 * MB);
  ushort* Abn2 = (ushort*)(ws + OFF_BN + 32 * MB);
  ushort* Bbn2 = (ushort*)(ws + OFF_BN + 48 * MB);
  ushort* th   = (ushort*)(ws + OFF_TH);
  ushort* Kgx  = (ushort*)(ws + OFF_KG);
  ushort* Vgx  = (ushort*)(ws + OFF_VG);
  ushort* yb   = (ushort*)(ws + OFF_YB);
  float*  out  = (float*)d_out;

  const size_t MODSTR = (size_t)16 * 262144;

  // 1) weights -> bf16
  WcvtArgs wa;
  for (int mod = 0; mod < 2; ++mod) {
    wa.src[mod * 4 + 0] = in(mod, 4);
    wa.src[mod * 4 + 1] = in(mod, 6);
    wa.src[mod * 4 + 2] = in(mod, 8);
    wa.src[mod * 4 + 3] = in(mod, 10);
  }
  wcvt8_k<<<dim3(512, 8), 256, 0, stream>>>(wa, wbf);

  // 2) fused dual-BN transpose
  bn2_k<<<dim3(32, 16, 32), 256, 0, stream>>>(
      rgb, flow,
      in(0, 0), in(0, 1), in(0, 2), in(0, 3),
      in(1, 0), in(1, 1), in(1, 2), in(1, 3),
      Abn1, Bbn1, Abn2, Bbn2);

  // 3) all six projections, one launch
  ProjArgs pa;
  for (int mod = 0; mod < 2; ++mod) {
    const ushort* wb4 = wbf + (size_t)mod * 4 * 131072;
    ushort* Abn = mod ? Abn2 : Abn1;
    ushort* Bbn = mod ? Bbn2 : Bbn1;
    pa.d[mod * 3 + 0] = {wb4,              Abn, in(mod, 5), th + mod * MODSTR,            0};
    pa.d[mod * 3 + 1] = {wb4 + 131072,     Bbn, in(mod, 7), Kgx + (size_t)mod * 16 * KINST, 1};
    pa.d[mod * 3 + 2] = {wb4 + 2 * 131072, Abn, in(mod, 9), Vgx + (size_t)mod * 16 * VINST, 2};
  }
  proj128_k<<<dim3(16, 96), 256, 0, stream>>>(pa);

  // 4) flash attention (both modules, in-block KV-split, XCD-chunked)
  flash_k<<<dim3(512), 256, 0, stream>>>(th, Kgx, Vgx, yb);

  // 5) W-projection + BN-residual epilogue
  for (int mod = 0; mod < 2; ++mod) {
    const ushort* wW = wbf + (size_t)(mod * 4 + 3) * 131072;
    const float* As = mod ? flow : rgb;
    wgemm_epi_k<<<dim3(16, 8, 16), 256, 0, stream>>>(
        yb + mod * MODSTR, wW, in(mod, 11), As,
        in(mod, 0), in(mod, 1), in(mod, 2), in(mod, 3),
        out + (size_t)mod * 16 * 512 * 1024);
  }
}